// Round 3
// baseline (261.955 us; speedup 1.0000x reference)
//
#include <hip/hip_runtime.h>
#include <hip/hip_bf16.h>

#define B_  8
#define C_  384
#define N_  1024
#define NH_ 12
#define HD_ 32
#define D3_ 1152   // 3*C

typedef __bf16 bf16x8 __attribute__((ext_vector_type(8)));
typedef float  f32x4  __attribute__((ext_vector_type(4)));

typedef const __attribute__((address_space(1))) unsigned int guint;
typedef __attribute__((address_space(3))) unsigned int luint;

__device__ __forceinline__ float b2f(ushort u) {
    return __uint_as_float(((unsigned int)u) << 16);
}
__device__ __forceinline__ ushort f2b(float f) {
    unsigned int i = __float_as_uint(f);
    unsigned int r = i + 0x7fffu + ((i >> 16) & 1u);  // RNE
    return (ushort)(r >> 16);
}

#if __has_builtin(__builtin_amdgcn_exp2f)
#define EXP2 __builtin_amdgcn_exp2f
#else
#define EXP2 exp2f
#endif

__device__ __forceinline__ void gl2lds16(const void* g, void* l) {
    __builtin_amdgcn_global_load_lds((guint*)g, (luint*)l, 16, 0, 0);
}

// ---------------------------------------------------------------------------
// prep: fp32 -> bf16 weight conversion.
// Wall[1152][384] = concat(q_w, kv_w); PW[384][384] = proj_w; ballf = concat biases.
// ---------------------------------------------------------------------------
__global__ __launch_bounds__(256) void prep(
    const float* __restrict__ q_w, const float* __restrict__ kv_w,
    const float* __restrict__ proj_w, const float* __restrict__ q_b,
    const float* __restrict__ kv_b, ushort* __restrict__ Wall,
    ushort* __restrict__ PW, float* __restrict__ ballf)
{
    const int NW4 = 110592, NP4 = 36864, NB4 = 288;
    int t = blockIdx.x * 256 + threadIdx.x;
    if (t < NW4) {
        int e = t * 4;
        float4 f = (e < 147456) ? *(const float4*)(q_w + e)
                                : *(const float4*)(kv_w + e - 147456);
        union { uint2 u; ushort s[4]; } o;
        o.s[0] = f2b(f.x); o.s[1] = f2b(f.y); o.s[2] = f2b(f.z); o.s[3] = f2b(f.w);
        *(uint2*)(Wall + e) = o.u;
    } else if (t < NW4 + NP4) {
        int e = (t - NW4) * 4;
        float4 f = *(const float4*)(proj_w + e);
        union { uint2 u; ushort s[4]; } o;
        o.s[0] = f2b(f.x); o.s[1] = f2b(f.y); o.s[2] = f2b(f.z); o.s[3] = f2b(f.w);
        *(uint2*)(PW + e) = o.u;
    } else if (t < NW4 + NP4 + NB4) {
        int e = (t - NW4 - NP4) * 4;
        float4 f = (e < 384) ? *(const float4*)(q_b + e)
                             : *(const float4*)(kv_b + e - 384);
        *(float4*)(ballf + e) = f;
    }
}

// ---------------------------------------------------------------------------
// xtrans: x[b][c][n] fp32 -> xT[b][n][c] bf16 (64x64 LDS tiles)
// ---------------------------------------------------------------------------
__global__ __launch_bounds__(256) void xtrans(
    const float* __restrict__ x, ushort* __restrict__ xT)
{
    const int b = blockIdx.z, n0 = blockIdx.x * 64, c0 = blockIdx.y * 64;
    __shared__ ushort T[64 * 72];
    const int tid = threadIdx.x;
    {
        int i = tid >> 2;            // c-local 0..63
        int ns = (tid & 3) * 16;     // n-local
        const float* src = x + ((size_t)b * C_ + c0 + i) * N_ + n0 + ns;
        #pragma unroll
        for (int k4 = 0; k4 < 4; ++k4) {
            float4 f = *(const float4*)(src + k4 * 4);
            T[(ns + k4 * 4 + 0) * 72 + i] = f2b(f.x);
            T[(ns + k4 * 4 + 1) * 72 + i] = f2b(f.y);
            T[(ns + k4 * 4 + 2) * 72 + i] = f2b(f.z);
            T[(ns + k4 * 4 + 3) * 72 + i] = f2b(f.w);
        }
    }
    __syncthreads();
    {
        int j = tid >> 2;            // n-local
        int cs = (tid & 3) * 16;     // c-local
        ushort* dst = xT + ((size_t)b * N_ + n0 + j) * C_ + c0 + cs;
        *(uint4*)dst       = *(const uint4*)&T[j * 72 + cs];
        *(uint4*)(dst + 8) = *(const uint4*)&T[j * 72 + cs + 8];
    }
}

// ---------------------------------------------------------------------------
// bias2: fragment-ordered, log2e-prescaled bias.
// biasL[((h*64+qs)*16+mc)*64+lane][j=t*4+r] = bf16(rpb[idx(q,m)][h] * log2e)
//   q = qs*16 + (lane>>4)*4 + r,  m = mc*64 + t*16 + (lane&15)
//   idx = (dy+31)*63 + (dx+31), computed analytically (no rel_index read).
// ---------------------------------------------------------------------------
__global__ __launch_bounds__(256) void bias2(
    const float* __restrict__ tab, ushort* __restrict__ biasL)
{
    const float C2 = 1.4426950408889634f;
    int gid = blockIdx.x * 256 + threadIdx.x;     // 786432 total
    int lane = gid & 63;
    int mc = (gid >> 6) & 15;
    int qs = (gid >> 10) & 63;
    int h  = gid >> 16;
    int quad = lane >> 4, l16 = lane & 15;
    union { uint4 u[2]; ushort us[16]; } o;
    #pragma unroll
    for (int t = 0; t < 4; ++t) {
        int m = mc * 64 + t * 16 + l16;
        int my = m >> 5, mx = m & 31;
        #pragma unroll
        for (int r = 0; r < 4; ++r) {
            int q = qs * 16 + quad * 4 + r;
            int dy = (q >> 5) - my + 31;
            int dx = (q & 31) - mx + 31;
            float v = tab[(size_t)(dy * 63 + dx) * NH_ + h] * C2;
            o.us[t * 4 + r] = f2b(v);
        }
    }
    ushort* dst = biasL + (size_t)gid * 16;
    *(uint4*)dst = o.u[0];
    *(uint4*)(dst + 8) = o.u[1];
}

// ---------------------------------------------------------------------------
// qkv_gemm2: m97-style 128x128 tile, global_load_lds staging.
// qkv[b][n][d] = sum_c Wall[d][c]*xT[b][n][c] + ballf[d]
// ---------------------------------------------------------------------------
__global__ __launch_bounds__(256) void qkv_gemm2(
    const ushort* __restrict__ xT, const ushort* __restrict__ Wall,
    const float* __restrict__ ballf, ushort* __restrict__ qkv)
{
    const int b = blockIdx.z, n0 = blockIdx.x * 128, d0 = blockIdx.y * 128;
    __shared__ ushort As[128 * 32];
    __shared__ ushort Bs[128 * 32];
    const int tid = threadIdx.x;
    const int lane = tid & 63, wave = tid >> 6;
    const int quad = lane >> 4, l16 = lane & 15;
    const int wn = (wave & 1) * 64, wd = (wave >> 1) * 64;

    f32x4 acc[4][4] = {};
    const ushort* xb = xT + ((size_t)b * N_ + n0) * C_;
    const ushort* wb = Wall + (size_t)d0 * C_;
    const int rowA = wave * 16 + (lane >> 2);
    const int coff = (lane & 3) * 8;

    for (int c0 = 0; c0 < C_; c0 += 32) {
        #pragma unroll
        for (int k = 0; k < 2; ++k) {
            gl2lds16(xb + (size_t)(k * 64 + rowA) * C_ + c0 + coff,
                     &As[(size_t)(k * 256 + wave * 64) * 8]);
            gl2lds16(wb + (size_t)(k * 64 + rowA) * C_ + c0 + coff,
                     &Bs[(size_t)(k * 256 + wave * 64) * 8]);
        }
        __syncthreads();
        bf16x8 af[4], bfr[4];
        #pragma unroll
        for (int i = 0; i < 4; ++i)
            af[i] = *(const bf16x8*)&As[(wn + i * 16 + l16) * 32 + quad * 8];
        #pragma unroll
        for (int j = 0; j < 4; ++j)
            bfr[j] = *(const bf16x8*)&Bs[(wd + j * 16 + l16) * 32 + quad * 8];
        #pragma unroll
        for (int i = 0; i < 4; ++i)
            #pragma unroll
            for (int j = 0; j < 4; ++j)
                acc[i][j] = __builtin_amdgcn_mfma_f32_16x16x32_bf16(af[i], bfr[j], acc[i][j], 0, 0, 0);
        __syncthreads();
    }

    const size_t ob = (size_t)b * N_ * D3_;
    #pragma unroll
    for (int j = 0; j < 4; ++j) {
        int d = d0 + wd + j * 16 + l16;
        float bv = ballf[d];
        #pragma unroll
        for (int i = 0; i < 4; ++i) {
            int nbase = n0 + wn + i * 16 + quad * 4;
            #pragma unroll
            for (int r = 0; r < 4; ++r)
                qkv[ob + (size_t)(nbase + r) * D3_ + d] = f2b(acc[i][j][r] + bv);
        }
    }
}

// ---------------------------------------------------------------------------
// vtrans: qkv V-part [b][n][768+vd] -> Vt[b*384+vd][n]  (64x64 LDS tiles)
// ---------------------------------------------------------------------------
__global__ __launch_bounds__(256) void vtrans(
    const ushort* __restrict__ qkv, ushort* __restrict__ Vt)
{
    const int b = blockIdx.z, n0 = blockIdx.x * 64, vd0 = blockIdx.y * 64;
    __shared__ ushort T[64 * 72];
    const int tid = threadIdx.x;
    {
        int i = tid >> 2;           // n-local
        int ds = (tid & 3) * 16;    // d-local
        const ushort* src = qkv + ((size_t)b * N_ + n0 + i) * D3_ + 768 + vd0 + ds;
        union { uint4 u; ushort s[8]; } a, bq;
        a.u  = *(const uint4*)src;
        bq.u = *(const uint4*)(src + 8);
        #pragma unroll
        for (int k = 0; k < 8; ++k) {
            T[(ds + k) * 72 + i]     = a.s[k];
            T[(ds + 8 + k) * 72 + i] = bq.s[k];
        }
    }
    __syncthreads();
    {
        int j = tid >> 2;           // d-local
        int ns = (tid & 3) * 16;    // n-local
        ushort* dst = Vt + (size_t)(b * 384 + vd0 + j) * N_ + n0 + ns;
        *(uint4*)dst       = *(const uint4*)&T[j * 72 + ns];
        *(uint4*)(dst + 8) = *(const uint4*)&T[j * 72 + ns + 8];
    }
}

// ---------------------------------------------------------------------------
// attn2: barrier-free. B-frags for K and V loaded straight from global (L2);
// fixed-max softmax (scores provably bounded); per-wave P LDS roundtrip with
// XOR swizzle (conflict-free); single final row-sum reduction.
// ---------------------------------------------------------------------------
__global__ __launch_bounds__(256) void attn2(
    const ushort* __restrict__ qkv, const ushort* __restrict__ Vt,
    const ushort* __restrict__ biasL, ushort* __restrict__ O)
{
    const int b = blockIdx.z, h = blockIdx.y, n0 = blockIdx.x * 64;
    __shared__ ushort Ps[4 * 16 * 72];

    const int tid = threadIdx.x;
    const int lane = tid & 63, wave = tid >> 6;
    const int quad = lane >> 4, l16 = lane & 15;
    const size_t bb = (size_t)b * N_ * D3_;

    // Q A-frag (row=l16, k=quad*8+j), held for whole kernel
    const int qrow = n0 + wave * 16 + l16;
    bf16x8 aq = *(const bf16x8*)(qkv + bb + (size_t)qrow * D3_ + h * HD_ + quad * 8);

    f32x4 oacc[2] = {};
    float rsum[4] = {0.f, 0.f, 0.f, 0.f};

    const int qs = blockIdx.x * 4 + wave;
    const ushort* bptr = biasL + (((size_t)h * 64 + qs) * 16 * 64 + lane) * 16;

    // K B-frag pointers: row m = t*16+l16, k = quad*8+j; advance 64 rows per chunk
    const ushort* kp0 = qkv + bb + (size_t)(0 * 16 + l16) * D3_ + 384 + h * HD_ + quad * 8;
    const ushort* kp1 = kp0 + (size_t)16 * D3_;
    const ushort* kp2 = kp0 + (size_t)32 * D3_;
    const ushort* kp3 = kp0 + (size_t)48 * D3_;
    // V B-frag pointers: Vt row d = dt*16+l16; col m advances 64 per chunk
    const ushort* vp0 = Vt + (size_t)(b * 384 + h * HD_ + l16) * N_ + quad * 8;
    const ushort* vp1 = vp0 + (size_t)16 * N_;

    ushort* Pw = &Ps[wave * 16 * 72];
    const float C1 = 0.17677669529663687f * 1.4426950408889634f;  // scale*log2e
    const f32x4 zero = {0.f, 0.f, 0.f, 0.f};

    for (int mc = 0; mc < 16; ++mc) {
        bf16x8 bk0 = *(const bf16x8*)kp0;
        bf16x8 bk1 = *(const bf16x8*)kp1;
        bf16x8 bk2 = *(const bf16x8*)kp2;
        bf16x8 bk3 = *(const bf16x8*)kp3;
        kp0 += (size_t)64 * D3_; kp1 += (size_t)64 * D3_;
        kp2 += (size_t)64 * D3_; kp3 += (size_t)64 * D3_;

        union { uint4 u[2]; ushort us[16]; } bw;
        bw.u[0] = *(const uint4*)bptr;
        bw.u[1] = *(const uint4*)(bptr + 8);
        bptr += 1024;

        f32x4 s[4];
        s[0] = __builtin_amdgcn_mfma_f32_16x16x32_bf16(aq, bk0, zero, 0, 0, 0);
        s[1] = __builtin_amdgcn_mfma_f32_16x16x32_bf16(aq, bk1, zero, 0, 0, 0);
        s[2] = __builtin_amdgcn_mfma_f32_16x16x32_bf16(aq, bk2, zero, 0, 0, 0);
        s[3] = __builtin_amdgcn_mfma_f32_16x16x32_bf16(aq, bk3, zero, 0, 0, 0);

        // p = exp2(s*C1 + biasC2); write P to LDS in swizzled A-layout
        #pragma unroll
        for (int t = 0; t < 4; ++t) {
            int colb = ((t ^ quad) * 16) + l16;
            #pragma unroll
            for (int r = 0; r < 4; ++r) {
                float p = EXP2(s[t][r] * C1 + b2f(bw.us[t * 4 + r]));
                rsum[r] += p;
                Pw[(quad * 4 + r) * 72 + colb] = f2b(p);
            }
        }

        #pragma unroll
        for (int kc = 0; kc < 2; ++kc) {
            int tb = (kc * 2 + (quad >> 1)) ^ (l16 >> 2);
            bf16x8 ap = *(const bf16x8*)&Pw[l16 * 72 + tb * 16 + (quad & 1) * 8];
            bf16x8 bv0 = *(const bf16x8*)(vp0 + mc * 64 + kc * 32);
            bf16x8 bv1 = *(const bf16x8*)(vp1 + mc * 64 + kc * 32);
            oacc[0] = __builtin_amdgcn_mfma_f32_16x16x32_bf16(ap, bv0, oacc[0], 0, 0, 0);
            oacc[1] = __builtin_amdgcn_mfma_f32_16x16x32_bf16(ap, bv1, oacc[1], 0, 0, 0);
        }
    }

    // final row-sum reduce across the 16 lanes holding each row's columns
    #pragma unroll
    for (int r = 0; r < 4; ++r) {
        float sum = rsum[r];
        #pragma unroll
        for (int off = 1; off < 16; off <<= 1)
            sum += __shfl_xor(sum, off, 64);
        rsum[r] = 1.0f / sum;
    }

    #pragma unroll
    for (int dt = 0; dt < 2; ++dt)
        #pragma unroll
        for (int r = 0; r < 4; ++r) {
            int q = n0 + wave * 16 + quad * 4 + r;
            O[(size_t)b * N_ * C_ + (size_t)q * C_ + h * HD_ + dt * 16 + l16] =
                f2b(oacc[dt][r] * rsum[r]);
        }
}

// ---------------------------------------------------------------------------
// proj_gemm: out[b][d][n] = sum_c PW[d][c]*O[b][n][c] + proj_b[d]  (out fp32)
// ---------------------------------------------------------------------------
__global__ __launch_bounds__(256) void proj_gemm(
    const ushort* __restrict__ O, const ushort* __restrict__ PW,
    const float* __restrict__ pb, float* __restrict__ out)
{
    const int b = blockIdx.z;
    const int n0 = blockIdx.x * 64;
    const int d0 = blockIdx.y * 64;

    __shared__ ushort As[64 * 40];  // [d][c]
    __shared__ ushort Bs[64 * 40];  // [n][c]

    const int tid = threadIdx.x;
    const int lane = tid & 63, wave = tid >> 6;
    const int quad = lane >> 4, l16 = lane & 15;

    f32x4 acc[4] = {};
    const ushort* Ob = O + (size_t)b * N_ * C_;

    for (int c0 = 0; c0 < C_; c0 += 32) {
        int rr = tid >> 2, cs = (tid & 3) * 8;
        *(uint4*)&As[rr * 40 + cs] = *(const uint4*)(PW + (size_t)(d0 + rr) * C_ + c0 + cs);
        *(uint4*)&Bs[rr * 40 + cs] = *(const uint4*)(Ob + (size_t)(n0 + rr) * C_ + c0 + cs);
        __syncthreads();

        bf16x8 a = *(const bf16x8*)&As[(wave * 16 + l16) * 40 + quad * 8];
        #pragma unroll
        for (int t = 0; t < 4; ++t) {
            bf16x8 bb = *(const bf16x8*)&Bs[(t * 16 + l16) * 40 + quad * 8];
            acc[t] = __builtin_amdgcn_mfma_f32_16x16x32_bf16(a, bb, acc[t], 0, 0, 0);
        }
        __syncthreads();
    }

    #pragma unroll
    for (int r = 0; r < 4; ++r) {
        int d = d0 + wave * 16 + quad * 4 + r;
        float bv = pb[d];
        #pragma unroll
        for (int t = 0; t < 4; ++t) {
            int n = n0 + t * 16 + l16;
            out[(size_t)b * C_ * N_ + (size_t)d * N_ + n] = acc[t][r] + bv;
        }
    }
}

// ---------------------------------------------------------------------------
extern "C" void kernel_launch(void* const* d_in, const int* in_sizes, int n_in,
                              void* d_out, int out_size, void* d_ws, size_t ws_size,
                              hipStream_t stream)
{
    const float* x      = (const float*)d_in[0];
    const float* q_w    = (const float*)d_in[1];
    const float* q_b    = (const float*)d_in[2];
    const float* kv_w   = (const float*)d_in[3];
    const float* kv_b   = (const float*)d_in[4];
    const float* proj_w = (const float*)d_in[5];
    const float* proj_b = (const float*)d_in[6];
    const float* rpb    = (const float*)d_in[7];
    float* out = (float*)d_out;

    char* ws = (char*)d_ws;
    ushort* qkv   = (ushort*)(ws);                       // 18,874,368
    ushort* biasL = (ushort*)(ws + 18874368);            // 25,165,824
    ushort* Vt    = (ushort*)(ws + 44040192);            //  6,291,456
    ushort* xT    = (ushort*)(ws + 50331648);            //  6,291,456 (reused as O)
    ushort* O     = xT;                                  //  alias: xT dead after qkv_gemm2
    ushort* Wall  = (ushort*)(ws + 56623104);            //    884,736
    ushort* PW    = (ushort*)(ws + 57507840);            //    294,912
    float*  ballf = (float*) (ws + 57802752);            //      4,608

    prep      <<<dim3(578), 256, 0, stream>>>(q_w, kv_w, proj_w, q_b, kv_b, Wall, PW, ballf);
    xtrans    <<<dim3(16, 6, B_), 256, 0, stream>>>(x, xT);
    bias2     <<<dim3(3072), 256, 0, stream>>>(rpb, biasL);
    qkv_gemm2 <<<dim3(8, 9, B_), 256, 0, stream>>>(xT, Wall, ballf, qkv);
    vtrans    <<<dim3(16, 6, B_), 256, 0, stream>>>(qkv, Vt);
    attn2     <<<dim3(16, NH_, B_), 256, 0, stream>>>(qkv, Vt, biasL, O);
    proj_gemm <<<dim3(16, 6, B_), 256, 0, stream>>>(O, PW, proj_b, out);
}

// Round 4
// 168.065 us; speedup vs baseline: 1.5587x; 1.5587x over previous
//
#include <hip/hip_runtime.h>
#include <hip/hip_bf16.h>

#define B_  8
#define C_  384
#define N_  1024
#define NH_ 12
#define HD_ 32
#define D3_ 1152   // 3*C

typedef __bf16 bf16x8 __attribute__((ext_vector_type(8)));
typedef float  f32x4  __attribute__((ext_vector_type(4)));

typedef const __attribute__((address_space(1))) unsigned int guint;
typedef __attribute__((address_space(3))) unsigned int luint;

__device__ __forceinline__ float b2f(ushort u) {
    return __uint_as_float(((unsigned int)u) << 16);
}
__device__ __forceinline__ ushort f2b(float f) {
    unsigned int i = __float_as_uint(f);
    unsigned int r = i + 0x7fffu + ((i >> 16) & 1u);  // RNE
    return (ushort)(r >> 16);
}

#if __has_builtin(__builtin_amdgcn_exp2f)
#define EXP2 __builtin_amdgcn_exp2f
#else
#define EXP2 exp2f
#endif

__device__ __forceinline__ void gl2lds16(const void* g, void* l) {
    __builtin_amdgcn_global_load_lds((guint*)g, (luint*)l, 16, 0, 0);
}

// ---------------------------------------------------------------------------
// setup: fused bias-expand + x-transpose + weight-conversion.
// Grid ranges: [0,3072) bias2, [3072,3840) xtrans, [3840,4418) prep.
// ---------------------------------------------------------------------------
__global__ __launch_bounds__(256) void setup(
    const float* __restrict__ x, const float* __restrict__ q_w,
    const float* __restrict__ kv_w, const float* __restrict__ proj_w,
    const float* __restrict__ q_b, const float* __restrict__ kv_b,
    const float* __restrict__ tab,
    ushort* __restrict__ xT, ushort* __restrict__ biasL,
    ushort* __restrict__ Wall, ushort* __restrict__ PW,
    float* __restrict__ ballf)
{
    __shared__ ushort T[64 * 72];
    const int bx = blockIdx.x, tid = threadIdx.x;

    if (bx < 3072) {
        // ---- bias expand, S^T fragment order, pre-scaled by log2e ----
        // biasL[(((h*64+qs)*16+mc)*64+lane)*16 + t*4+r]:
        //   q = qs*16 + (lane&15), m = mc*64 + t*16 + (lane>>4)*4 + r
        const float C2 = 1.4426950408889634f;
        int gid = bx * 256 + tid;
        int lane = gid & 63;
        int mc = (gid >> 6) & 15;
        int qs = (gid >> 10) & 63;
        int h  = gid >> 16;
        int quad = lane >> 4, l16 = lane & 15;
        int q = qs * 16 + l16;
        int qy = q >> 5, qx = q & 31;
        union { uint4 u[2]; ushort us[16]; } o;
        #pragma unroll
        for (int t = 0; t < 4; ++t) {
            #pragma unroll
            for (int r = 0; r < 4; ++r) {
                int m = mc * 64 + t * 16 + quad * 4 + r;
                int my = m >> 5, mx = m & 31;
                int dy = qy - my + 31, dx = qx - mx + 31;
                float v = tab[(size_t)(dy * 63 + dx) * NH_ + h] * C2;
                o.us[t * 4 + r] = f2b(v);
            }
        }
        ushort* dst = biasL + (size_t)gid * 16;
        *(uint4*)dst = o.u[0];
        *(uint4*)(dst + 8) = o.u[1];
    } else if (bx < 3840) {
        // ---- xtrans: x[b][c][n] fp32 -> xT[b][n][c] bf16 ----
        int t = bx - 3072;
        int nx = t & 15, cy = (t >> 4) % 6, b = t / 96;
        int n0 = nx * 64, c0 = cy * 64;
        {
            int i = tid >> 2;            // c-local
            int ns = (tid & 3) * 16;     // n-local
            const float* src = x + ((size_t)b * C_ + c0 + i) * N_ + n0 + ns;
            #pragma unroll
            for (int k4 = 0; k4 < 4; ++k4) {
                float4 f = *(const float4*)(src + k4 * 4);
                T[(ns + k4 * 4 + 0) * 72 + i] = f2b(f.x);
                T[(ns + k4 * 4 + 1) * 72 + i] = f2b(f.y);
                T[(ns + k4 * 4 + 2) * 72 + i] = f2b(f.z);
                T[(ns + k4 * 4 + 3) * 72 + i] = f2b(f.w);
            }
        }
        __syncthreads();
        {
            int j = tid >> 2;            // n-local
            int cs = (tid & 3) * 16;     // c-local
            ushort* dst = xT + ((size_t)b * N_ + n0 + j) * C_ + c0 + cs;
            *(uint4*)dst       = *(const uint4*)&T[j * 72 + cs];
            *(uint4*)(dst + 8) = *(const uint4*)&T[j * 72 + cs + 8];
        }
    } else {
        // ---- prep: weights fp32 -> bf16; bias concat fp32 ----
        const int NW4 = 110592, NP4 = 36864, NB4 = 288;
        int t = (bx - 3840) * 256 + tid;
        if (t < NW4) {
            int e = t * 4;
            float4 f = (e < 147456) ? *(const float4*)(q_w + e)
                                    : *(const float4*)(kv_w + e - 147456);
            union { uint2 u; ushort s[4]; } o;
            o.s[0] = f2b(f.x); o.s[1] = f2b(f.y); o.s[2] = f2b(f.z); o.s[3] = f2b(f.w);
            *(uint2*)(Wall + e) = o.u;
        } else if (t < NW4 + NP4) {
            int e = (t - NW4) * 4;
            float4 f = *(const float4*)(proj_w + e);
            union { uint2 u; ushort s[4]; } o;
            o.s[0] = f2b(f.x); o.s[1] = f2b(f.y); o.s[2] = f2b(f.z); o.s[3] = f2b(f.w);
            *(uint2*)(PW + e) = o.u;
        } else if (t < NW4 + NP4 + NB4) {
            int e = (t - NW4 - NP4) * 4;
            float4 f = (e < 384) ? *(const float4*)(q_b + e)
                                 : *(const float4*)(kv_b + e - 384);
            *(float4*)(ballf + e) = f;
        }
    }
}

// ---------------------------------------------------------------------------
// qkv_gemm3: 128x128 tile, global_load_lds, XOR-swizzled LDS.
// Writes per-head layouts: Qt/Kt/Vtmp[b][h][n][32].
// ---------------------------------------------------------------------------
__global__ __launch_bounds__(256) void qkv_gemm3(
    const ushort* __restrict__ xT, const ushort* __restrict__ Wall,
    const float* __restrict__ ballf, ushort* __restrict__ Qt,
    ushort* __restrict__ Kt, ushort* __restrict__ Vtmp)
{
    const int b = blockIdx.z, n0 = blockIdx.x * 128, d0 = blockIdx.y * 128;
    __shared__ ushort As[128 * 32];
    __shared__ ushort Bs[128 * 32];
    const int tid = threadIdx.x;
    const int lane = tid & 63, wave = tid >> 6;
    const int quad = lane >> 4, l16 = lane & 15;
    const int wn = (wave & 1) * 64, wd = (wave >> 1) * 64;

    f32x4 acc[4][4] = {};
    const ushort* xb = xT + ((size_t)b * N_ + n0) * C_;
    const ushort* wb = Wall + (size_t)d0 * C_;
    const int rowA = wave * 16 + (lane >> 2);
    const int fstage = ((lane >> 2) ^ (lane >> 4)) & 3;           // staging swizzle
    const int coff = ((lane & 3) ^ fstage) * 8;
    const int fread = ((l16 & 3) ^ ((l16 >> 2) & 3));             // read swizzle

    for (int c0 = 0; c0 < C_; c0 += 32) {
        #pragma unroll
        for (int k = 0; k < 2; ++k) {
            gl2lds16(xb + (size_t)(k * 64 + rowA) * C_ + c0 + coff,
                     &As[(size_t)(k * 256 + wave * 64) * 8]);
            gl2lds16(wb + (size_t)(k * 64 + rowA) * C_ + c0 + coff,
                     &Bs[(size_t)(k * 256 + wave * 64) * 8]);
        }
        __syncthreads();
        bf16x8 af[4], bfr[4];
        #pragma unroll
        for (int i = 0; i < 4; ++i)
            af[i] = *(const bf16x8*)&As[(wn + i * 16 + l16) * 32 + (quad ^ fread) * 8];
        #pragma unroll
        for (int j = 0; j < 4; ++j)
            bfr[j] = *(const bf16x8*)&Bs[(wd + j * 16 + l16) * 32 + (quad ^ fread) * 8];
        #pragma unroll
        for (int i = 0; i < 4; ++i)
            #pragma unroll
            for (int j = 0; j < 4; ++j)
                acc[i][j] = __builtin_amdgcn_mfma_f32_16x16x32_bf16(af[i], bfr[j], acc[i][j], 0, 0, 0);
        __syncthreads();
    }

    // epilogue: D[row=n][col=d]; route to Qt/Kt/Vtmp[b][h][n][dc]
    ushort* dst; int reg0;
    if (d0 < 384)      { dst = Qt;   reg0 = 0; }
    else if (d0 < 768) { dst = Kt;   reg0 = 384; }
    else               { dst = Vtmp; reg0 = 768; }
    const int hb = (d0 - reg0) >> 5;
    #pragma unroll
    for (int j = 0; j < 4; ++j) {
        int dloc = wd + j * 16 + l16;
        int h = hb + (dloc >> 5), dc = dloc & 31;
        float bv = ballf[d0 + dloc];
        size_t base = ((size_t)(b * NH_ + h) * N_) * 32 + dc;
        #pragma unroll
        for (int i = 0; i < 4; ++i) {
            int nbase = n0 + wn + i * 16 + quad * 4;
            #pragma unroll
            for (int r = 0; r < 4; ++r)
                dst[base + (size_t)(nbase + r) * 32] = f2b(acc[i][j][r] + bv);
        }
    }
}

// ---------------------------------------------------------------------------
// vtrans: Vtmp[b][h][m][dc] -> Vtc[((bh*16+mc)*2+kc)][dc 32][mm 32]
// ---------------------------------------------------------------------------
__global__ __launch_bounds__(256) void vtrans(
    const ushort* __restrict__ Vtmp, ushort* __restrict__ Vtc)
{
    const int mc = blockIdx.x, bh = blockIdx.y;
    __shared__ ushort T[32 * 80];
    const int tid = threadIdx.x;
    {
        int row = tid >> 2;            // m-local 0..63
        int dcs = (tid & 3) * 8;
        union { uint4 u; ushort s[8]; } a;
        a.u = *(const uint4*)(Vtmp + ((size_t)bh * N_ + mc * 64 + row) * 32 + dcs);
        #pragma unroll
        for (int k = 0; k < 8; ++k) T[(dcs + k) * 80 + row] = a.s[k];
    }
    __syncthreads();
    {
        int kc = tid >> 7, dc = (tid >> 2) & 31, mm8 = (tid & 3) * 8;
        *(uint4*)(Vtc + ((size_t)(bh * 16 + mc) * 2 + kc) * 1024 + dc * 32 + mm8) =
            *(const uint4*)&T[dc * 80 + kc * 32 + mm8];
    }
}

// ---------------------------------------------------------------------------
// attn3: barrier-free flash attention, S^T orientation.
// Block = (b, h, 128 q-rows); wave = 2 q-strips of 16.
// K/V/Q/bias read direct from global (line-contained frag loads);
// LDS only for the per-wave P C->B-layout roundtrip (XOR-swizzled b64/b128).
// ---------------------------------------------------------------------------
__global__ __launch_bounds__(256) void attn3(
    const ushort* __restrict__ Qt, const ushort* __restrict__ Kt,
    const ushort* __restrict__ Vtc, const ushort* __restrict__ biasL,
    ushort* __restrict__ O)
{
    const int bid = blockIdx.x;      // b*96 + h*8 + nx  (XCD key = nx)
    const int nx = bid & 7;
    const int h  = (bid >> 3) % NH_;
    const int b  = bid / 96;
    __shared__ ushort Pa[8192];      // 4 waves x 2 strips x 16 x 64

    const int tid = threadIdx.x;
    const int lane = tid & 63, wave = tid >> 6;
    const int quad = lane >> 4, l16 = lane & 15;
    const int bh = b * NH_ + h;
    const int qs0 = nx * 8 + wave * 2;

    const ushort* Kbh = Kt + (size_t)bh * N_ * 32;
    const ushort* Vbh = Vtc + (size_t)bh * 16 * 2048;

    // Q B-frags (col=q=l16, k=dc=quad*8+j), one per strip, held all kernel
    bf16x8 qf[2];
    #pragma unroll
    for (int st = 0; st < 2; ++st)
        qf[st] = *(const bf16x8*)(Qt + ((size_t)bh * N_ + (qs0 + st) * 16 + l16) * 32 + quad * 8);

    const ushort* bp[2];
    #pragma unroll
    for (int st = 0; st < 2; ++st)
        bp[st] = biasL + ((size_t)(h * 64 + qs0 + st) * 16 * 64 + lane) * 16;

    f32x4 oacc[2][2] = {};
    float rs[2] = {0.f, 0.f};

    ushort* PwBase = &Pa[wave * 2048];
    const int pswz = l16 & 0xE;
    const float C1 = 0.17677669529663687f * 1.4426950408889634f;  // scale*log2e
    const f32x4 zero = {0.f, 0.f, 0.f, 0.f};

    for (int mc = 0; mc < 16; ++mc) {
        // K A-frags: A[m=l16][k=quad*8+j] per 16-row tile (1KB line-contained)
        const ushort* kp = Kbh + mc * 64 * 32;
        bf16x8 k0 = *(const bf16x8*)(kp + (0 * 16 + l16) * 32 + quad * 8);
        bf16x8 k1 = *(const bf16x8*)(kp + (1 * 16 + l16) * 32 + quad * 8);
        bf16x8 k2 = *(const bf16x8*)(kp + (2 * 16 + l16) * 32 + quad * 8);
        bf16x8 k3 = *(const bf16x8*)(kp + (3 * 16 + l16) * 32 + quad * 8);
        // V^T A-frags: A[dc=dt*16+l16][m=kc*32+quad*8+j] (1KB line-contained)
        const ushort* vp = Vbh + mc * 2048;
        bf16x8 va[2][2];
        #pragma unroll
        for (int kc = 0; kc < 2; ++kc)
            #pragma unroll
            for (int dt = 0; dt < 2; ++dt)
                va[kc][dt] = *(const bf16x8*)(vp + kc * 1024 + (dt * 16 + l16) * 32 + quad * 8);
        // bias (fragment-ordered, contiguous 32B per lane)
        union { uint4 u[2]; ushort us[16]; } bw[2];
        #pragma unroll
        for (int st = 0; st < 2; ++st) {
            bw[st].u[0] = *(const uint4*)(bp[st] + mc * 1024);
            bw[st].u[1] = *(const uint4*)(bp[st] + mc * 1024 + 8);
        }

        #pragma unroll
        for (int st = 0; st < 2; ++st) {
            // S^T strip: D[row=m][col=q]
            f32x4 s0 = __builtin_amdgcn_mfma_f32_16x16x32_bf16(k0, qf[st], zero, 0, 0, 0);
            f32x4 s1 = __builtin_amdgcn_mfma_f32_16x16x32_bf16(k1, qf[st], zero, 0, 0, 0);
            f32x4 s2 = __builtin_amdgcn_mfma_f32_16x16x32_bf16(k2, qf[st], zero, 0, 0, 0);
            f32x4 s3 = __builtin_amdgcn_mfma_f32_16x16x32_bf16(k3, qf[st], zero, 0, 0, 0);

            ushort* Pw = PwBase + st * 1024;
            f32x4 sv[4] = {s0, s1, s2, s3};
            #pragma unroll
            for (int t = 0; t < 4; ++t) {
                float p0 = EXP2(sv[t][0] * C1 + b2f(bw[st].us[t * 4 + 0]));
                float p1 = EXP2(sv[t][1] * C1 + b2f(bw[st].us[t * 4 + 1]));
                float p2 = EXP2(sv[t][2] * C1 + b2f(bw[st].us[t * 4 + 2]));
                float p3 = EXP2(sv[t][3] * C1 + b2f(bw[st].us[t * 4 + 3]));
                rs[st] += (p0 + p1) + (p2 + p3);
                uint2 w;
                w.x = (unsigned)f2b(p0) | ((unsigned)f2b(p1) << 16);
                w.y = (unsigned)f2b(p2) | ((unsigned)f2b(p3) << 16);
                *(uint2*)(Pw + l16 * 64 + (((t * 4 + quad) ^ pswz) * 4)) = w;
            }
            // PV: O^T[dc][q] += V^T . P   (B-frag P from swizzled LDS)
            #pragma unroll
            for (int kc = 0; kc < 2; ++kc) {
                bf16x8 pb = *(const bf16x8*)(Pw + l16 * 64 + (((kc * 8 + quad * 2) ^ pswz) * 4));
                oacc[st][0] = __builtin_amdgcn_mfma_f32_16x16x32_bf16(va[kc][0], pb, oacc[st][0], 0, 0, 0);
                oacc[st][1] = __builtin_amdgcn_mfma_f32_16x16x32_bf16(va[kc][1], pb, oacc[st][1], 0, 0, 0);
            }
        }
    }

    // row-sum: q fixed per lane; reduce across the 4 quads holding its m-slices
    #pragma unroll
    for (int st = 0; st < 2; ++st) {
        float s = rs[st];
        s += __shfl_xor(s, 16, 64);
        s += __shfl_xor(s, 32, 64);
        rs[st] = 1.0f / s;
    }

    // epilogue: O[b][q][h*32+dc], packed b64 stores
    #pragma unroll
    for (int st = 0; st < 2; ++st) {
        int q = (qs0 + st) * 16 + l16;
        ushort* ob = O + ((size_t)(b * N_ + q)) * C_ + h * HD_;
        #pragma unroll
        for (int dt = 0; dt < 2; ++dt) {
            float v0 = oacc[st][dt][0] * rs[st];
            float v1 = oacc[st][dt][1] * rs[st];
            float v2 = oacc[st][dt][2] * rs[st];
            float v3 = oacc[st][dt][3] * rs[st];
            uint2 w;
            w.x = (unsigned)f2b(v0) | ((unsigned)f2b(v1) << 16);
            w.y = (unsigned)f2b(v2) | ((unsigned)f2b(v3) << 16);
            *(uint2*)(ob + dt * 16 + quad * 4) = w;
        }
    }
}

// ---------------------------------------------------------------------------
// proj_gemm3: 128x128 tile, global_load_lds. A=PW[d][c], B=O[n][c].
// out[b][d][n] fp32 = acc + pb[d], coalesced along n.
// ---------------------------------------------------------------------------
__global__ __launch_bounds__(256) void proj_gemm3(
    const ushort* __restrict__ O, const ushort* __restrict__ PW,
    const float* __restrict__ pb, float* __restrict__ out)
{
    const int b = blockIdx.z, n0 = blockIdx.x * 128, d0 = blockIdx.y * 128;
    __shared__ ushort As[128 * 32];
    __shared__ ushort Bs[128 * 32];
    const int tid = threadIdx.x;
    const int lane = tid & 63, wave = tid >> 6;
    const int quad = lane >> 4, l16 = lane & 15;
    const int wa = (wave & 1) * 64, wb = (wave >> 1) * 64;

    f32x4 acc[4][4] = {};
    const ushort* ab = PW + (size_t)d0 * C_;
    const ushort* bbp = O + ((size_t)b * N_ + n0) * C_;
    const int rowA = wave * 16 + (lane >> 2);
    const int fstage = ((lane >> 2) ^ (lane >> 4)) & 3;
    const int coff = ((lane & 3) ^ fstage) * 8;
    const int fread = ((l16 & 3) ^ ((l16 >> 2) & 3));

    for (int c0 = 0; c0 < C_; c0 += 32) {
        #pragma unroll
        for (int k = 0; k < 2; ++k) {
            gl2lds16(ab + (size_t)(k * 64 + rowA) * C_ + c0 + coff,
                     &As[(size_t)(k * 256 + wave * 64) * 8]);
            gl2lds16(bbp + (size_t)(k * 64 + rowA) * C_ + c0 + coff,
                     &Bs[(size_t)(k * 256 + wave * 64) * 8]);
        }
        __syncthreads();
        bf16x8 af[4], bfr[4];
        #pragma unroll
        for (int i = 0; i < 4; ++i)
            af[i] = *(const bf16x8*)&As[(wa + i * 16 + l16) * 32 + (quad ^ fread) * 8];
        #pragma unroll
        for (int j = 0; j < 4; ++j)
            bfr[j] = *(const bf16x8*)&Bs[(wb + j * 16 + l16) * 32 + (quad ^ fread) * 8];
        #pragma unroll
        for (int i = 0; i < 4; ++i)
            #pragma unroll
            for (int j = 0; j < 4; ++j)
                acc[i][j] = __builtin_amdgcn_mfma_f32_16x16x32_bf16(af[i], bfr[j], acc[i][j], 0, 0, 0);
        __syncthreads();
    }

    #pragma unroll
    for (int i = 0; i < 4; ++i) {
        #pragma unroll
        for (int r = 0; r < 4; ++r) {
            int d = d0 + wa + i * 16 + quad * 4 + r;
            float bv = pb[d];
            float* op = out + ((size_t)b * C_ + d) * N_ + n0 + wb;
            #pragma unroll
            for (int j = 0; j < 4; ++j)
                op[j * 16 + l16] = acc[i][j][r] + bv;
        }
    }
}

// ---------------------------------------------------------------------------
extern "C" void kernel_launch(void* const* d_in, const int* in_sizes, int n_in,
                              void* d_out, int out_size, void* d_ws, size_t ws_size,
                              hipStream_t stream)
{
    const float* x      = (const float*)d_in[0];
    const float* q_w    = (const float*)d_in[1];
    const float* q_b    = (const float*)d_in[2];
    const float* kv_w   = (const float*)d_in[3];
    const float* kv_b   = (const float*)d_in[4];
    const float* proj_w = (const float*)d_in[5];
    const float* proj_b = (const float*)d_in[6];
    const float* rpb    = (const float*)d_in[7];
    float* out = (float*)d_out;

    char* ws = (char*)d_ws;
    ushort* xT    = (ushort*)(ws);                       //  6,291,456
    ushort* Qt    = (ushort*)(ws +  6291456);            //  6,291,456
    ushort* Kt    = (ushort*)(ws + 12582912);            //  6,291,456
    ushort* Vtmp  = (ushort*)(ws + 18874368);            //  6,291,456  (-> O after vtrans)
    ushort* Vtc   = (ushort*)(ws + 25165824);            //  6,291,456
    ushort* biasL = (ushort*)(ws + 31457280);            // 25,165,824
    ushort* Wall  = (ushort*)(ws + 56623104);            //    884,736
    ushort* PW    = (ushort*)(ws + 57507840);            //    294,912
    float*  ballf = (float*) (ws + 57802752);            //      4,608
    ushort* O     = Vtmp;                                // alias (Vtmp dead after vtrans)

    setup      <<<dim3(4418), 256, 0, stream>>>(x, q_w, kv_w, proj_w, q_b, kv_b, rpb,
                                                xT, biasL, Wall, PW, ballf);
    qkv_gemm3  <<<dim3(8, 9, B_), 256, 0, stream>>>(xT, Wall, ballf, Qt, Kt, Vtmp);
    vtrans     <<<dim3(16, 96), 256, 0, stream>>>(Vtmp, Vtc);
    attn3      <<<dim3(768), 256, 0, stream>>>(Qt, Kt, Vtc, biasL, O);
    proj_gemm3 <<<dim3(8, 3, B_), 256, 0, stream>>>(O, PW, proj_b, out);
}

// Round 5
// 157.017 us; speedup vs baseline: 1.6683x; 1.0704x over previous
//
#include <hip/hip_runtime.h>
#include <hip/hip_bf16.h>

#define B_  8
#define C_  384
#define N_  1024
#define NH_ 12
#define HD_ 32
#define D3_ 1152   // 3*C

typedef __bf16 bf16x8 __attribute__((ext_vector_type(8)));
typedef float  f32x4  __attribute__((ext_vector_type(4)));

typedef const __attribute__((address_space(1))) unsigned int guint;
typedef __attribute__((address_space(3))) unsigned int luint;

__device__ __forceinline__ float b2f(ushort u) {
    return __uint_as_float(((unsigned int)u) << 16);
}
__device__ __forceinline__ ushort f2b(float f) {
    unsigned int i = __float_as_uint(f);
    unsigned int r = i + 0x7fffu + ((i >> 16) & 1u);  // RNE
    return (ushort)(r >> 16);
}

#if __has_builtin(__builtin_amdgcn_exp2f)
#define EXP2 __builtin_amdgcn_exp2f
#else
#define EXP2 exp2f
#endif

__device__ __forceinline__ void gl2lds16(const void* g, void* l) {
    __builtin_amdgcn_global_load_lds((guint*)g, (luint*)l, 16, 0, 0);
}

#define C1_ 0.25505654204433796f   // scale * log2e = 0.176776... * 1.442695...
#define C2_ 1.4426950408889634f    // log2e

// ---------------------------------------------------------------------------
// setup: x-transpose + weight conversion + bias-table prep.
// Grid: [0,768) xtrans, [768,1346) prep, [1346,1358) tabT.
// tabT[h][dyf*63+dx] = rpb[((62-dyf)*63+dx)*12 + h] * log2e   (dy-flipped, fp32)
// ---------------------------------------------------------------------------
__global__ __launch_bounds__(256) void setup(
    const float* __restrict__ x, const float* __restrict__ q_w,
    const float* __restrict__ kv_w, const float* __restrict__ proj_w,
    const float* __restrict__ q_b, const float* __restrict__ kv_b,
    const float* __restrict__ tab,
    ushort* __restrict__ xT, float* __restrict__ tabT,
    ushort* __restrict__ Wall, ushort* __restrict__ PW,
    float* __restrict__ ballf)
{
    __shared__ ushort T[64 * 72];
    const int bx = blockIdx.x, tid = threadIdx.x;

    if (bx < 768) {
        // ---- xtrans: x[b][c][n] fp32 -> xT[b][n][c] bf16 ----
        int t = bx;
        int nx = t & 15, cy = (t >> 4) % 6, b = t / 96;
        int n0 = nx * 64, c0 = cy * 64;
        {
            int i = tid >> 2;            // c-local
            int ns = (tid & 3) * 16;     // n-local
            const float* src = x + ((size_t)b * C_ + c0 + i) * N_ + n0 + ns;
            #pragma unroll
            for (int k4 = 0; k4 < 4; ++k4) {
                float4 f = *(const float4*)(src + k4 * 4);
                T[(ns + k4 * 4 + 0) * 72 + i] = f2b(f.x);
                T[(ns + k4 * 4 + 1) * 72 + i] = f2b(f.y);
                T[(ns + k4 * 4 + 2) * 72 + i] = f2b(f.z);
                T[(ns + k4 * 4 + 3) * 72 + i] = f2b(f.w);
            }
        }
        __syncthreads();
        {
            int j = tid >> 2;            // n-local
            int cs = (tid & 3) * 16;     // c-local
            ushort* dst = xT + ((size_t)b * N_ + n0 + j) * C_ + c0 + cs;
            *(uint4*)dst       = *(const uint4*)&T[j * 72 + cs];
            *(uint4*)(dst + 8) = *(const uint4*)&T[j * 72 + cs + 8];
        }
    } else if (bx < 1346) {
        // ---- prep: weights fp32 -> bf16; bias concat fp32 ----
        const int NW4 = 110592, NP4 = 36864, NB4 = 288;
        int t = (bx - 768) * 256 + tid;
        if (t < NW4) {
            int e = t * 4;
            float4 f = (e < 147456) ? *(const float4*)(q_w + e)
                                    : *(const float4*)(kv_w + e - 147456);
            union { uint2 u; ushort s[4]; } o;
            o.s[0] = f2b(f.x); o.s[1] = f2b(f.y); o.s[2] = f2b(f.z); o.s[3] = f2b(f.w);
            *(uint2*)(Wall + e) = o.u;
        } else if (t < NW4 + NP4) {
            int e = (t - NW4) * 4;
            float4 f = *(const float4*)(proj_w + e);
            union { uint2 u; ushort s[4]; } o;
            o.s[0] = f2b(f.x); o.s[1] = f2b(f.y); o.s[2] = f2b(f.z); o.s[3] = f2b(f.w);
            *(uint2*)(PW + e) = o.u;
        } else if (t < NW4 + NP4 + NB4) {
            int e = (t - NW4 - NP4) * 4;
            float4 f = (e < 384) ? *(const float4*)(q_b + e)
                                 : *(const float4*)(kv_b + e - 384);
            *(float4*)(ballf + e) = f;
        }
    } else {
        // ---- tabT: per-head flipped+scaled relative-position table ----
        int h = bx - 1346;
        for (int i = tid; i < 3969; i += 256) {
            int dyf = i / 63;
            int src = 3906 + i - 126 * dyf;        // (62-dyf)*63 + dx
            tabT[h * 3969 + i] = tab[(size_t)src * NH_ + h] * C2_;
        }
    }
}

// ---------------------------------------------------------------------------
// qkv_gemm3: 128x128 tile, global_load_lds, XOR-swizzled LDS.
// Writes per-head layouts: Qt/Kt/Vtmp[b][h][n][32]. Q is pre-scaled by C1.
// ---------------------------------------------------------------------------
__global__ __launch_bounds__(256) void qkv_gemm3(
    const ushort* __restrict__ xT, const ushort* __restrict__ Wall,
    const float* __restrict__ ballf, ushort* __restrict__ Qt,
    ushort* __restrict__ Kt, ushort* __restrict__ Vtmp)
{
    const int b = blockIdx.z, n0 = blockIdx.x * 128, d0 = blockIdx.y * 128;
    __shared__ ushort As[128 * 32];
    __shared__ ushort Bs[128 * 32];
    const int tid = threadIdx.x;
    const int lane = tid & 63, wave = tid >> 6;
    const int quad = lane >> 4, l16 = lane & 15;
    const int wn = (wave & 1) * 64, wd = (wave >> 1) * 64;

    f32x4 acc[4][4] = {};
    const ushort* xb = xT + ((size_t)b * N_ + n0) * C_;
    const ushort* wb = Wall + (size_t)d0 * C_;
    const int rowA = wave * 16 + (lane >> 2);
    const int fstage = ((lane >> 2) ^ (lane >> 4)) & 3;           // staging swizzle
    const int coff = ((lane & 3) ^ fstage) * 8;
    const int fread = ((l16 & 3) ^ ((l16 >> 2) & 3));             // read swizzle

    for (int c0 = 0; c0 < C_; c0 += 32) {
        #pragma unroll
        for (int k = 0; k < 2; ++k) {
            gl2lds16(xb + (size_t)(k * 64 + rowA) * C_ + c0 + coff,
                     &As[(size_t)(k * 256 + wave * 64) * 8]);
            gl2lds16(wb + (size_t)(k * 64 + rowA) * C_ + c0 + coff,
                     &Bs[(size_t)(k * 256 + wave * 64) * 8]);
        }
        __syncthreads();
        bf16x8 af[4], bfr[4];
        #pragma unroll
        for (int i = 0; i < 4; ++i)
            af[i] = *(const bf16x8*)&As[(wn + i * 16 + l16) * 32 + (quad ^ fread) * 8];
        #pragma unroll
        for (int j = 0; j < 4; ++j)
            bfr[j] = *(const bf16x8*)&Bs[(wd + j * 16 + l16) * 32 + (quad ^ fread) * 8];
        #pragma unroll
        for (int i = 0; i < 4; ++i)
            #pragma unroll
            for (int j = 0; j < 4; ++j)
                acc[i][j] = __builtin_amdgcn_mfma_f32_16x16x32_bf16(af[i], bfr[j], acc[i][j], 0, 0, 0);
        __syncthreads();
    }

    // epilogue: D[row=n][col=d]; route to Qt/Kt/Vtmp[b][h][n][dc]
    ushort* dst; int reg0;
    if (d0 < 384)      { dst = Qt;   reg0 = 0; }
    else if (d0 < 768) { dst = Kt;   reg0 = 384; }
    else               { dst = Vtmp; reg0 = 768; }
    const float sc = (d0 < 384) ? C1_ : 1.0f;   // fold scale*log2e into Q
    const int hb = (d0 - reg0) >> 5;
    #pragma unroll
    for (int j = 0; j < 4; ++j) {
        int dloc = wd + j * 16 + l16;
        int h = hb + (dloc >> 5), dc = dloc & 31;
        float bv = ballf[d0 + dloc];
        size_t base = ((size_t)(b * NH_ + h) * N_) * 32 + dc;
        #pragma unroll
        for (int i = 0; i < 4; ++i) {
            int nbase = n0 + wn + i * 16 + quad * 4;
            #pragma unroll
            for (int r = 0; r < 4; ++r)
                dst[base + (size_t)(nbase + r) * 32] = f2b((acc[i][j][r] + bv) * sc);
        }
    }
}

// ---------------------------------------------------------------------------
// vtrans: Vtmp[b][h][m][dc] -> Vtc[((bh*16+mc)*2+kc)][dc 32][mm 32]
// ---------------------------------------------------------------------------
__global__ __launch_bounds__(256) void vtrans(
    const ushort* __restrict__ Vtmp, ushort* __restrict__ Vtc)
{
    const int mc = blockIdx.x, bh = blockIdx.y;
    __shared__ ushort T[32 * 80];
    const int tid = threadIdx.x;
    {
        int row = tid >> 2;            // m-local 0..63
        int dcs = (tid & 3) * 8;
        union { uint4 u; ushort s[8]; } a;
        a.u = *(const uint4*)(Vtmp + ((size_t)bh * N_ + mc * 64 + row) * 32 + dcs);
        #pragma unroll
        for (int k = 0; k < 8; ++k) T[(dcs + k) * 80 + row] = a.s[k];
    }
    __syncthreads();
    {
        int kc = tid >> 7, dc = (tid >> 2) & 31, mm8 = (tid & 3) * 8;
        *(uint4*)(Vtc + ((size_t)(bh * 16 + mc) * 2 + kc) * 1024 + dc * 32 + mm8) =
            *(const uint4*)&T[dc * 80 + kc * 32 + mm8];
    }
}

// ---------------------------------------------------------------------------
// attn4: flash attention, S^T orientation, bias table resident in LDS.
// Block = (b, h, 128 q-rows); wave = 2 q-strips of 16.
// Bias enters as MFMA C-operand (fp32 from LDS table, Toeplitz addressing).
// Q pre-scaled by scale*log2e; p = exp2(s) directly.
// ---------------------------------------------------------------------------
__global__ __launch_bounds__(256) void attn4(
    const ushort* __restrict__ Qt, const ushort* __restrict__ Kt,
    const ushort* __restrict__ Vtc, const float* __restrict__ tabT,
    ushort* __restrict__ O)
{
    const int bid = blockIdx.x;      // (b*12+h) + 96*nx : same-(b,h) share an XCD slot
    const int bh96 = bid % 96;
    const int nx = bid / 96;
    const int b = bh96 / 12, h = bh96 % 12;

    __shared__ float tabL[3972];
    __shared__ ushort Pa[8192];      // 4 waves x 2 strips x 16 x 64

    const int tid = threadIdx.x;
    const int lane = tid & 63, wave = tid >> 6;
    const int quad = lane >> 4, l16 = lane & 15;
    const int bh = b * NH_ + h;

    // stage this head's bias table into LDS (fp32, pre-scaled, dy-flipped)
    {
        const float* th = tabT + h * 3969;
        for (int i = tid; i < 3969; i += 256) tabL[i] = th[i];
    }
    __syncthreads();

    const int qs0 = nx * 8 + wave * 2;
    const ushort* Kbh = Kt + (size_t)bh * N_ * 32;
    const ushort* Vbh = Vtc + (size_t)bh * 16 * 2048;

    // Q B-frags (col=q=l16, k=dc=quad*8+j), one per strip
    bf16x8 qf[2];
    int ib[2];
    #pragma unroll
    for (int st = 0; st < 2; ++st) {
        int q = (qs0 + st) * 16 + l16;
        qf[st] = *(const bf16x8*)(Qt + ((size_t)bh * N_ + q) * 32 + quad * 8);
        int qy = q >> 5, qx = q & 31;
        ib[st] = (31 - qy) * 63 + qx + 31;   // flipped-table base index
    }

    // Toeplitz offsets per (t,r) fragment slot (loop-invariant)
    int off_tr[16];
    #pragma unroll
    for (int t = 0; t < 4; ++t)
        #pragma unroll
        for (int r = 0; r < 4; ++r) {
            int ml = t * 16 + quad * 4 + r;
            off_tr[t * 4 + r] = (ml >> 5) * 63 - (ml & 31);
        }

    f32x4 oacc[2][2] = {};
    float rs[2] = {0.f, 0.f};

    ushort* PwBase = &Pa[wave * 2048];
    const int pswz = l16 & 0xE;

    for (int mc = 0; mc < 16; ++mc) {
        // K A-frags: A[m=l16][k=quad*8+j] per 16-row tile (1KB line-contained)
        const ushort* kp = Kbh + mc * 64 * 32;
        bf16x8 k0 = *(const bf16x8*)(kp + (0 * 16 + l16) * 32 + quad * 8);
        bf16x8 k1 = *(const bf16x8*)(kp + (1 * 16 + l16) * 32 + quad * 8);
        bf16x8 k2 = *(const bf16x8*)(kp + (2 * 16 + l16) * 32 + quad * 8);
        bf16x8 k3 = *(const bf16x8*)(kp + (3 * 16 + l16) * 32 + quad * 8);
        // V^T A-frags: A[dc=dt*16+l16][m=kc*32+quad*8+j] (1KB line-contained)
        const ushort* vp = Vbh + mc * 2048;
        bf16x8 va[2][2];
        #pragma unroll
        for (int kc = 0; kc < 2; ++kc)
            #pragma unroll
            for (int dt = 0; dt < 2; ++dt)
                va[kc][dt] = *(const bf16x8*)(vp + kc * 1024 + (dt * 16 + l16) * 32 + quad * 8);

        #pragma unroll
        for (int st = 0; st < 2; ++st) {
            const int ibm = ib[st] + mc * 126;
            // bias as MFMA C-init (S^T layout: row m = t*16+quad*4+r, col q = l16)
            f32x4 cb[4];
            #pragma unroll
            for (int t = 0; t < 4; ++t) {
                cb[t][0] = tabL[ibm + off_tr[t * 4 + 0]];
                cb[t][1] = tabL[ibm + off_tr[t * 4 + 1]];
                cb[t][2] = tabL[ibm + off_tr[t * 4 + 2]];
                cb[t][3] = tabL[ibm + off_tr[t * 4 + 3]];
            }
            f32x4 s0 = __builtin_amdgcn_mfma_f32_16x16x32_bf16(k0, qf[st], cb[0], 0, 0, 0);
            f32x4 s1 = __builtin_amdgcn_mfma_f32_16x16x32_bf16(k1, qf[st], cb[1], 0, 0, 0);
            f32x4 s2 = __builtin_amdgcn_mfma_f32_16x16x32_bf16(k2, qf[st], cb[2], 0, 0, 0);
            f32x4 s3 = __builtin_amdgcn_mfma_f32_16x16x32_bf16(k3, qf[st], cb[3], 0, 0, 0);

            ushort* Pw = PwBase + st * 1024;
            f32x4 sv[4] = {s0, s1, s2, s3};
            #pragma unroll
            for (int t = 0; t < 4; ++t) {
                float p0 = EXP2(sv[t][0]);
                float p1 = EXP2(sv[t][1]);
                float p2 = EXP2(sv[t][2]);
                float p3 = EXP2(sv[t][3]);
                rs[st] += (p0 + p1) + (p2 + p3);
                uint2 w;
                w.x = (unsigned)f2b(p0) | ((unsigned)f2b(p1) << 16);
                w.y = (unsigned)f2b(p2) | ((unsigned)f2b(p3) << 16);
                *(uint2*)(Pw + l16 * 64 + (((t * 4 + quad) ^ pswz) * 4)) = w;
            }
            // PV: O^T[dc][q] += V^T . P   (B-frag P from swizzled LDS)
            #pragma unroll
            for (int kc = 0; kc < 2; ++kc) {
                bf16x8 pb = *(const bf16x8*)(Pw + l16 * 64 + (((kc * 8 + quad * 2) ^ pswz) * 4));
                oacc[st][0] = __builtin_amdgcn_mfma_f32_16x16x32_bf16(va[kc][0], pb, oacc[st][0], 0, 0, 0);
                oacc[st][1] = __builtin_amdgcn_mfma_f32_16x16x32_bf16(va[kc][1], pb, oacc[st][1], 0, 0, 0);
            }
        }
    }

    // row-sum: q fixed per lane; reduce across the 4 quads holding its m-slices
    #pragma unroll
    for (int st = 0; st < 2; ++st) {
        float s = rs[st];
        s += __shfl_xor(s, 16, 64);
        s += __shfl_xor(s, 32, 64);
        rs[st] = 1.0f / s;
    }

    // epilogue: O[b][q][h*32+dc], packed b64 stores
    #pragma unroll
    for (int st = 0; st < 2; ++st) {
        int q = (qs0 + st) * 16 + l16;
        ushort* ob = O + ((size_t)(b * N_ + q)) * C_ + h * HD_;
        #pragma unroll
        for (int dt = 0; dt < 2; ++dt) {
            float v0 = oacc[st][dt][0] * rs[st];
            float v1 = oacc[st][dt][1] * rs[st];
            float v2 = oacc[st][dt][2] * rs[st];
            float v3 = oacc[st][dt][3] * rs[st];
            uint2 w;
            w.x = (unsigned)f2b(v0) | ((unsigned)f2b(v1) << 16);
            w.y = (unsigned)f2b(v2) | ((unsigned)f2b(v3) << 16);
            *(uint2*)(ob + dt * 16 + quad * 4) = w;
        }
    }
}

// ---------------------------------------------------------------------------
// proj_gemm3: 128x128 tile, global_load_lds. A=PW[d][c], B=O[n][c].
// out[b][d][n] fp32 = acc + pb[d], coalesced along n.
// ---------------------------------------------------------------------------
__global__ __launch_bounds__(256) void proj_gemm3(
    const ushort* __restrict__ O, const ushort* __restrict__ PW,
    const float* __restrict__ pb, float* __restrict__ out)
{
    const int b = blockIdx.z, n0 = blockIdx.x * 128, d0 = blockIdx.y * 128;
    __shared__ ushort As[128 * 32];
    __shared__ ushort Bs[128 * 32];
    const int tid = threadIdx.x;
    const int lane = tid & 63, wave = tid >> 6;
    const int quad = lane >> 4, l16 = lane & 15;
    const int wa = (wave & 1) * 64, wb = (wave >> 1) * 64;

    f32x4 acc[4][4] = {};
    const ushort* ab = PW + (size_t)d0 * C_;
    const ushort* bbp = O + ((size_t)b * N_ + n0) * C_;
    const int rowA = wave * 16 + (lane >> 2);
    const int fstage = ((lane >> 2) ^ (lane >> 4)) & 3;
    const int coff = ((lane & 3) ^ fstage) * 8;
    const int fread = ((l16 & 3) ^ ((l16 >> 2) & 3));

    for (int c0 = 0; c0 < C_; c0 += 32) {
        #pragma unroll
        for (int k = 0; k < 2; ++k) {
            gl2lds16(ab + (size_t)(k * 64 + rowA) * C_ + c0 + coff,
                     &As[(size_t)(k * 256 + wave * 64) * 8]);
            gl2lds16(bbp + (size_t)(k * 64 + rowA) * C_ + c0 + coff,
                     &Bs[(size_t)(k * 256 + wave * 64) * 8]);
        }
        __syncthreads();
        bf16x8 af[4], bfr[4];
        #pragma unroll
        for (int i = 0; i < 4; ++i)
            af[i] = *(const bf16x8*)&As[(wa + i * 16 + l16) * 32 + (quad ^ fread) * 8];
        #pragma unroll
        for (int j = 0; j < 4; ++j)
            bfr[j] = *(const bf16x8*)&Bs[(wb + j * 16 + l16) * 32 + (quad ^ fread) * 8];
        #pragma unroll
        for (int i = 0; i < 4; ++i)
            #pragma unroll
            for (int j = 0; j < 4; ++j)
                acc[i][j] = __builtin_amdgcn_mfma_f32_16x16x32_bf16(af[i], bfr[j], acc[i][j], 0, 0, 0);
        __syncthreads();
    }

    #pragma unroll
    for (int i = 0; i < 4; ++i) {
        #pragma unroll
        for (int r = 0; r < 4; ++r) {
            int d = d0 + wa + i * 16 + quad * 4 + r;
            float bv = pb[d];
            float* op = out + ((size_t)b * C_ + d) * N_ + n0 + wb;
            #pragma unroll
            for (int j = 0; j < 4; ++j)
                op[j * 16 + l16] = acc[i][j][r] + bv;
        }
    }
}

// ---------------------------------------------------------------------------
extern "C" void kernel_launch(void* const* d_in, const int* in_sizes, int n_in,
                              void* d_out, int out_size, void* d_ws, size_t ws_size,
                              hipStream_t stream)
{
    const float* x      = (const float*)d_in[0];
    const float* q_w    = (const float*)d_in[1];
    const float* q_b    = (const float*)d_in[2];
    const float* kv_w   = (const float*)d_in[3];
    const float* kv_b   = (const float*)d_in[4];
    const float* proj_w = (const float*)d_in[5];
    const float* proj_b = (const float*)d_in[6];
    const float* rpb    = (const float*)d_in[7];
    float* out = (float*)d_out;

    char* ws = (char*)d_ws;
    ushort* xT    = (ushort*)(ws);                       //  6,291,456
    ushort* Qt    = (ushort*)(ws +  6291456);            //  6,291,456
    ushort* Kt    = (ushort*)(ws + 12582912);            //  6,291,456
    ushort* Vtmp  = (ushort*)(ws + 18874368);            //  6,291,456  (-> O after vtrans)
    ushort* Vtc   = (ushort*)(ws + 25165824);            //  6,291,456
    float*  tabT  = (float*) (ws + 31457280);            //    190,512
    ushort* Wall  = (ushort*)(ws + 31647808);            //    884,736
    ushort* PW    = (ushort*)(ws + 32532544);            //    294,912
    float*  ballf = (float*) (ws + 32827456);            //      4,608
    ushort* O     = Vtmp;                                // alias (Vtmp dead after vtrans)

    setup      <<<dim3(1358), 256, 0, stream>>>(x, q_w, kv_w, proj_w, q_b, kv_b, rpb,
                                                xT, tabT, Wall, PW, ballf);
    qkv_gemm3  <<<dim3(8, 9, B_), 256, 0, stream>>>(xT, Wall, ballf, Qt, Kt, Vtmp);
    vtrans     <<<dim3(16, 96), 256, 0, stream>>>(Vtmp, Vtc);
    attn4      <<<dim3(768), 256, 0, stream>>>(Qt, Kt, Vtc, tabT, O);
    proj_gemm3 <<<dim3(8, 3, B_), 256, 0, stream>>>(O, PW, proj_b, out);
}

// Round 6
// 152.520 us; speedup vs baseline: 1.7175x; 1.0295x over previous
//
#include <hip/hip_runtime.h>
#include <hip/hip_bf16.h>

#define B_  8
#define C_  384
#define N_  1024
#define NH_ 12
#define HD_ 32
#define D3_ 1152   // 3*C

typedef __bf16 bf16x8 __attribute__((ext_vector_type(8)));
typedef __bf16 bf16x2 __attribute__((ext_vector_type(2)));
typedef float  f32x4  __attribute__((ext_vector_type(4)));

typedef const __attribute__((address_space(1))) unsigned int guint;
typedef __attribute__((address_space(3))) unsigned int luint;

__device__ __forceinline__ float b2f(ushort u) {
    return __uint_as_float(((unsigned int)u) << 16);
}
__device__ __forceinline__ ushort f2b(float f) {
    unsigned int i = __float_as_uint(f);
    unsigned int r = i + 0x7fffu + ((i >> 16) & 1u);  // RNE
    return (ushort)(r >> 16);
}
// packed fp32x2 -> bf16x2 (RNE); HW instr on gfx950 if builtin exists
__device__ __forceinline__ unsigned pk2(float a, float b) {
#if __has_builtin(__builtin_amdgcn_cvt_pk_bf16_f32)
    bf16x2 t = __builtin_amdgcn_cvt_pk_bf16_f32(a, b);
    return __builtin_bit_cast(unsigned, t);
#else
    return (unsigned)f2b(a) | ((unsigned)f2b(b) << 16);
#endif
}

#if __has_builtin(__builtin_amdgcn_exp2f)
#define EXP2 __builtin_amdgcn_exp2f
#else
#define EXP2 exp2f
#endif

__device__ __forceinline__ void gl2lds16(const void* g, void* l) {
    __builtin_amdgcn_global_load_lds((guint*)g, (luint*)l, 16, 0, 0);
}

#define C1_ 0.25505654204433796f   // scale * log2e
#define C2_ 1.4426950408889634f    // log2e

// ---------------------------------------------------------------------------
// setup: x-transpose + weight conversion + bias-table prep.
// Grid: [0,768) xtrans, [768,1346) prep, [1346,1358) tabT.
// ---------------------------------------------------------------------------
__global__ __launch_bounds__(256) void setup(
    const float* __restrict__ x, const float* __restrict__ q_w,
    const float* __restrict__ kv_w, const float* __restrict__ proj_w,
    const float* __restrict__ q_b, const float* __restrict__ kv_b,
    const float* __restrict__ tab,
    ushort* __restrict__ xT, float* __restrict__ tabT,
    ushort* __restrict__ Wall, ushort* __restrict__ PW,
    float* __restrict__ ballf)
{
    __shared__ ushort T[64 * 72];
    const int bx = blockIdx.x, tid = threadIdx.x;

    if (bx < 768) {
        // ---- xtrans: x[b][c][n] fp32 -> xT[b][n][c] bf16 ----
        int t = bx;
        int nx = t & 15, cy = (t >> 4) % 6, b = t / 96;
        int n0 = nx * 64, c0 = cy * 64;
        {
            int i = tid >> 2;            // c-local
            int ns = (tid & 3) * 16;     // n-local
            const float* src = x + ((size_t)b * C_ + c0 + i) * N_ + n0 + ns;
            #pragma unroll
            for (int k4 = 0; k4 < 4; ++k4) {
                float4 f = *(const float4*)(src + k4 * 4);
                T[(ns + k4 * 4 + 0) * 72 + i] = f2b(f.x);
                T[(ns + k4 * 4 + 1) * 72 + i] = f2b(f.y);
                T[(ns + k4 * 4 + 2) * 72 + i] = f2b(f.z);
                T[(ns + k4 * 4 + 3) * 72 + i] = f2b(f.w);
            }
        }
        __syncthreads();
        {
            int j = tid >> 2;            // n-local
            int cs = (tid & 3) * 16;     // c-local
            ushort* dst = xT + ((size_t)b * N_ + n0 + j) * C_ + c0 + cs;
            *(uint4*)dst       = *(const uint4*)&T[j * 72 + cs];
            *(uint4*)(dst + 8) = *(const uint4*)&T[j * 72 + cs + 8];
        }
    } else if (bx < 1346) {
        // ---- prep: weights fp32 -> bf16; bias concat fp32 ----
        const int NW4 = 110592, NP4 = 36864, NB4 = 288;
        int t = (bx - 768) * 256 + tid;
        if (t < NW4) {
            int e = t * 4;
            float4 f = (e < 147456) ? *(const float4*)(q_w + e)
                                    : *(const float4*)(kv_w + e - 147456);
            union { uint2 u; ushort s[4]; } o;
            o.u.x = pk2(f.x, f.y); o.u.y = pk2(f.z, f.w);
            *(uint2*)(Wall + e) = o.u;
        } else if (t < NW4 + NP4) {
            int e = (t - NW4) * 4;
            float4 f = *(const float4*)(proj_w + e);
            union { uint2 u; ushort s[4]; } o;
            o.u.x = pk2(f.x, f.y); o.u.y = pk2(f.z, f.w);
            *(uint2*)(PW + e) = o.u;
        } else if (t < NW4 + NP4 + NB4) {
            int e = (t - NW4 - NP4) * 4;
            float4 f = (e < 384) ? *(const float4*)(q_b + e)
                                 : *(const float4*)(kv_b + e - 384);
            *(float4*)(ballf + e) = f;
        }
    } else {
        // ---- tabT: per-head flipped+scaled relative-position table ----
        int h = bx - 1346;
        for (int i = tid; i < 3969; i += 256) {
            int dyf = i / 63;
            int src = 3906 + i - 126 * dyf;        // (62-dyf)*63 + dx
            tabT[h * 3969 + i] = tab[(size_t)src * NH_ + h] * C2_;
        }
    }
}

// ---------------------------------------------------------------------------
// qkv_gemm4: 128x128 tile, global_load_lds, XOR-swizzled LDS.
// Q/K epilogue -> Qt/Kt[b][h][n][32] (Q pre-scaled by scale*log2e).
// V epilogue  -> Vtc[((bh*16+mc)*2+kc)][dc][mm] directly (fused transpose,
//                packed uint2 stores: consecutive n == consecutive mm).
// ---------------------------------------------------------------------------
__global__ __launch_bounds__(256) void qkv_gemm4(
    const ushort* __restrict__ xT, const ushort* __restrict__ Wall,
    const float* __restrict__ ballf, ushort* __restrict__ Qt,
    ushort* __restrict__ Kt, ushort* __restrict__ Vtc)
{
    const int b = blockIdx.z, n0 = blockIdx.x * 128, d0 = blockIdx.y * 128;
    __shared__ ushort As[128 * 32];
    __shared__ ushort Bs[128 * 32];
    const int tid = threadIdx.x;
    const int lane = tid & 63, wave = tid >> 6;
    const int quad = lane >> 4, l16 = lane & 15;
    const int wn = (wave & 1) * 64, wd = (wave >> 1) * 64;

    f32x4 acc[4][4] = {};
    const ushort* xb = xT + ((size_t)b * N_ + n0) * C_;
    const ushort* wb = Wall + (size_t)d0 * C_;
    const int rowA = wave * 16 + (lane >> 2);
    const int fstage = ((lane >> 2) ^ (lane >> 4)) & 3;           // staging swizzle
    const int coff = ((lane & 3) ^ fstage) * 8;
    const int fread = ((l16 & 3) ^ ((l16 >> 2) & 3));             // read swizzle

    for (int c0 = 0; c0 < C_; c0 += 32) {
        #pragma unroll
        for (int k = 0; k < 2; ++k) {
            gl2lds16(xb + (size_t)(k * 64 + rowA) * C_ + c0 + coff,
                     &As[(size_t)(k * 256 + wave * 64) * 8]);
            gl2lds16(wb + (size_t)(k * 64 + rowA) * C_ + c0 + coff,
                     &Bs[(size_t)(k * 256 + wave * 64) * 8]);
        }
        __syncthreads();
        bf16x8 af[4], bfr[4];
        #pragma unroll
        for (int i = 0; i < 4; ++i)
            af[i] = *(const bf16x8*)&As[(wn + i * 16 + l16) * 32 + (quad ^ fread) * 8];
        #pragma unroll
        for (int j = 0; j < 4; ++j)
            bfr[j] = *(const bf16x8*)&Bs[(wd + j * 16 + l16) * 32 + (quad ^ fread) * 8];
        #pragma unroll
        for (int i = 0; i < 4; ++i)
            #pragma unroll
            for (int j = 0; j < 4; ++j)
                acc[i][j] = __builtin_amdgcn_mfma_f32_16x16x32_bf16(af[i], bfr[j], acc[i][j], 0, 0, 0);
        __syncthreads();
    }

    if (d0 < 768) {
        // Q/K: per-head [n][dc] layout, scalar stores
        ushort* dst = (d0 < 384) ? Qt : Kt;
        const float sc = (d0 < 384) ? C1_ : 1.0f;
        const int hb = ((d0 < 384) ? d0 : d0 - 384) >> 5;
        #pragma unroll
        for (int j = 0; j < 4; ++j) {
            int dloc = wd + j * 16 + l16;
            int h = hb + (dloc >> 5), dc = dloc & 31;
            float bv = ballf[d0 + dloc];
            size_t base = ((size_t)(b * NH_ + h) * N_) * 32 + dc;
            #pragma unroll
            for (int i = 0; i < 4; ++i) {
                int nbase = n0 + wn + i * 16 + quad * 4;
                #pragma unroll
                for (int r = 0; r < 4; ++r)
                    dst[base + (size_t)(nbase + r) * 32] = f2b((acc[i][j][r] + bv) * sc);
            }
        }
    } else {
        // V: fused transpose into Vtc[((bh*16+mc)*2+kc)*1024 + dc*32 + mm]
        #pragma unroll
        for (int j = 0; j < 4; ++j) {
            int dloc = wd + j * 16 + l16;
            int vd = d0 - 768 + dloc;
            int h = vd >> 5, dc = vd & 31;
            float bv = ballf[d0 + dloc];
            size_t hbase = (size_t)(b * NH_ + h) * 32768 + dc * 32;
            #pragma unroll
            for (int i = 0; i < 4; ++i) {
                int n = n0 + wn + i * 16 + quad * 4;
                size_t cbase = hbase + (size_t)((n >> 5)) * 1024 + (n & 31);
                uint2 w;
                w.x = pk2(acc[i][j][0] + bv, acc[i][j][1] + bv);
                w.y = pk2(acc[i][j][2] + bv, acc[i][j][3] + bv);
                *(uint2*)(Vtc + cbase) = w;
            }
        }
    }
}

// ---------------------------------------------------------------------------
// attn4: flash attention, S^T orientation, bias table resident in LDS.
// Block = (b, h, 128 q-rows); wave = 2 q-strips of 16.
// Bias enters as MFMA C-operand (fp32 from LDS table, Toeplitz addressing).
// Q pre-scaled by scale*log2e; p = exp2(s) directly.
// ---------------------------------------------------------------------------
__global__ __launch_bounds__(256) void attn4(
    const ushort* __restrict__ Qt, const ushort* __restrict__ Kt,
    const ushort* __restrict__ Vtc, const float* __restrict__ tabT,
    ushort* __restrict__ O)
{
    const int bid = blockIdx.x;      // (b*12+h) + 96*nx
    const int bh96 = bid % 96;
    const int nx = bid / 96;
    const int b = bh96 / 12, h = bh96 % 12;

    __shared__ float tabL[3972];
    __shared__ ushort Pa[8192];      // 4 waves x 2 strips x 16 x 64

    const int tid = threadIdx.x;
    const int lane = tid & 63, wave = tid >> 6;
    const int quad = lane >> 4, l16 = lane & 15;
    const int bh = b * NH_ + h;

    // stage this head's bias table into LDS (fp32, pre-scaled, dy-flipped)
    {
        const float* th = tabT + h * 3969;
        for (int i = tid; i < 3969; i += 256) tabL[i] = th[i];
    }
    __syncthreads();

    const int qs0 = nx * 8 + wave * 2;
    const ushort* Kbh = Kt + (size_t)bh * N_ * 32;
    const ushort* Vbh = Vtc + (size_t)bh * 16 * 2048;

    // Q B-frags (col=q=l16, k=dc=quad*8+j), one per strip
    bf16x8 qf[2];
    int ib[2];
    #pragma unroll
    for (int st = 0; st < 2; ++st) {
        int q = (qs0 + st) * 16 + l16;
        qf[st] = *(const bf16x8*)(Qt + ((size_t)bh * N_ + q) * 32 + quad * 8);
        int qy = q >> 5, qx = q & 31;
        ib[st] = (31 - qy) * 63 + qx + 31;   // flipped-table base index
    }

    // Toeplitz offsets per (t,r) fragment slot (loop-invariant)
    int off_tr[16];
    #pragma unroll
    for (int t = 0; t < 4; ++t)
        #pragma unroll
        for (int r = 0; r < 4; ++r) {
            int ml = t * 16 + quad * 4 + r;
            off_tr[t * 4 + r] = (ml >> 5) * 63 - (ml & 31);
        }

    f32x4 oacc[2][2] = {};
    float rs[2] = {0.f, 0.f};

    ushort* PwBase = &Pa[wave * 2048];
    const int pswz = l16 & 0xE;

    for (int mc = 0; mc < 16; ++mc) {
        // K A-frags: A[m=l16][k=quad*8+j] per 16-row tile (1KB line-contained)
        const ushort* kp = Kbh + mc * 64 * 32;
        bf16x8 k0 = *(const bf16x8*)(kp + (0 * 16 + l16) * 32 + quad * 8);
        bf16x8 k1 = *(const bf16x8*)(kp + (1 * 16 + l16) * 32 + quad * 8);
        bf16x8 k2 = *(const bf16x8*)(kp + (2 * 16 + l16) * 32 + quad * 8);
        bf16x8 k3 = *(const bf16x8*)(kp + (3 * 16 + l16) * 32 + quad * 8);
        // V^T A-frags: A[dc=dt*16+l16][m=kc*32+quad*8+j] (1KB line-contained)
        const ushort* vp = Vbh + mc * 2048;
        bf16x8 va[2][2];
        #pragma unroll
        for (int kc = 0; kc < 2; ++kc)
            #pragma unroll
            for (int dt = 0; dt < 2; ++dt)
                va[kc][dt] = *(const bf16x8*)(vp + kc * 1024 + (dt * 16 + l16) * 32 + quad * 8);

        #pragma unroll
        for (int st = 0; st < 2; ++st) {
            const int ibm = ib[st] + mc * 126;
            // bias as MFMA C-init (S^T layout: row m = t*16+quad*4+r, col q = l16)
            f32x4 cb[4];
            #pragma unroll
            for (int t = 0; t < 4; ++t) {
                cb[t][0] = tabL[ibm + off_tr[t * 4 + 0]];
                cb[t][1] = tabL[ibm + off_tr[t * 4 + 1]];
                cb[t][2] = tabL[ibm + off_tr[t * 4 + 2]];
                cb[t][3] = tabL[ibm + off_tr[t * 4 + 3]];
            }
            f32x4 s0 = __builtin_amdgcn_mfma_f32_16x16x32_bf16(k0, qf[st], cb[0], 0, 0, 0);
            f32x4 s1 = __builtin_amdgcn_mfma_f32_16x16x32_bf16(k1, qf[st], cb[1], 0, 0, 0);
            f32x4 s2 = __builtin_amdgcn_mfma_f32_16x16x32_bf16(k2, qf[st], cb[2], 0, 0, 0);
            f32x4 s3 = __builtin_amdgcn_mfma_f32_16x16x32_bf16(k3, qf[st], cb[3], 0, 0, 0);

            ushort* Pw = PwBase + st * 1024;
            f32x4 sv[4] = {s0, s1, s2, s3};
            #pragma unroll
            for (int t = 0; t < 4; ++t) {
                float p0 = EXP2(sv[t][0]);
                float p1 = EXP2(sv[t][1]);
                float p2 = EXP2(sv[t][2]);
                float p3 = EXP2(sv[t][3]);
                rs[st] += (p0 + p1) + (p2 + p3);
                uint2 w;
                w.x = pk2(p0, p1);
                w.y = pk2(p2, p3);
                *(uint2*)(Pw + l16 * 64 + (((t * 4 + quad) ^ pswz) * 4)) = w;
            }
            // PV: O^T[dc][q] += V^T . P   (B-frag P from swizzled LDS)
            #pragma unroll
            for (int kc = 0; kc < 2; ++kc) {
                bf16x8 pb = *(const bf16x8*)(Pw + l16 * 64 + (((kc * 8 + quad * 2) ^ pswz) * 4));
                oacc[st][0] = __builtin_amdgcn_mfma_f32_16x16x32_bf16(va[kc][0], pb, oacc[st][0], 0, 0, 0);
                oacc[st][1] = __builtin_amdgcn_mfma_f32_16x16x32_bf16(va[kc][1], pb, oacc[st][1], 0, 0, 0);
            }
        }
    }

    // row-sum: q fixed per lane; reduce across the 4 quads holding its m-slices
    #pragma unroll
    for (int st = 0; st < 2; ++st) {
        float s = rs[st];
        s += __shfl_xor(s, 16, 64);
        s += __shfl_xor(s, 32, 64);
        rs[st] = 1.0f / s;
    }

    // epilogue: O[b][q][h*32+dc], packed b64 stores
    #pragma unroll
    for (int st = 0; st < 2; ++st) {
        int q = (qs0 + st) * 16 + l16;
        ushort* ob = O + ((size_t)(b * N_ + q)) * C_ + h * HD_;
        #pragma unroll
        for (int dt = 0; dt < 2; ++dt) {
            uint2 w;
            w.x = pk2(oacc[st][dt][0] * rs[st], oacc[st][dt][1] * rs[st]);
            w.y = pk2(oacc[st][dt][2] * rs[st], oacc[st][dt][3] * rs[st]);
            *(uint2*)(ob + dt * 16 + quad * 4) = w;
        }
    }
}

// ---------------------------------------------------------------------------
// proj_gemm3: 128x128 tile, global_load_lds. A=PW[d][c], B=O[n][c].
// out[b][d][n] fp32 = acc + pb[d], coalesced along n.
// ---------------------------------------------------------------------------
__global__ __launch_bounds__(256) void proj_gemm3(
    const ushort* __restrict__ O, const ushort* __restrict__ PW,
    const float* __restrict__ pb, float* __restrict__ out)
{
    const int b = blockIdx.z, n0 = blockIdx.x * 128, d0 = blockIdx.y * 128;
    __shared__ ushort As[128 * 32];
    __shared__ ushort Bs[128 * 32];
    const int tid = threadIdx.x;
    const int lane = tid & 63, wave = tid >> 6;
    const int quad = lane >> 4, l16 = lane & 15;
    const int wa = (wave & 1) * 64, wb = (wave >> 1) * 64;

    f32x4 acc[4][4] = {};
    const ushort* ab = PW + (size_t)d0 * C_;
    const ushort* bbp = O + ((size_t)b * N_ + n0) * C_;
    const int rowA = wave * 16 + (lane >> 2);
    const int fstage = ((lane >> 2) ^ (lane >> 4)) & 3;
    const int coff = ((lane & 3) ^ fstage) * 8;
    const int fread = ((l16 & 3) ^ ((l16 >> 2) & 3));

    for (int c0 = 0; c0 < C_; c0 += 32) {
        #pragma unroll
        for (int k = 0; k < 2; ++k) {
            gl2lds16(ab + (size_t)(k * 64 + rowA) * C_ + c0 + coff,
                     &As[(size_t)(k * 256 + wave * 64) * 8]);
            gl2lds16(bbp + (size_t)(k * 64 + rowA) * C_ + c0 + coff,
                     &Bs[(size_t)(k * 256 + wave * 64) * 8]);
        }
        __syncthreads();
        bf16x8 af[4], bfr[4];
        #pragma unroll
        for (int i = 0; i < 4; ++i)
            af[i] = *(const bf16x8*)&As[(wa + i * 16 + l16) * 32 + (quad ^ fread) * 8];
        #pragma unroll
        for (int j = 0; j < 4; ++j)
            bfr[j] = *(const bf16x8*)&Bs[(wb + j * 16 + l16) * 32 + (quad ^ fread) * 8];
        #pragma unroll
        for (int i = 0; i < 4; ++i)
            #pragma unroll
            for (int j = 0; j < 4; ++j)
                acc[i][j] = __builtin_amdgcn_mfma_f32_16x16x32_bf16(af[i], bfr[j], acc[i][j], 0, 0, 0);
        __syncthreads();
    }

    #pragma unroll
    for (int i = 0; i < 4; ++i) {
        #pragma unroll
        for (int r = 0; r < 4; ++r) {
            int d = d0 + wa + i * 16 + quad * 4 + r;
            float bv = pb[d];
            float* op = out + ((size_t)b * C_ + d) * N_ + n0 + wb;
            #pragma unroll
            for (int j = 0; j < 4; ++j)
                op[j * 16 + l16] = acc[i][j][r] + bv;
        }
    }
}

// ---------------------------------------------------------------------------
extern "C" void kernel_launch(void* const* d_in, const int* in_sizes, int n_in,
                              void* d_out, int out_size, void* d_ws, size_t ws_size,
                              hipStream_t stream)
{
    const float* x      = (const float*)d_in[0];
    const float* q_w    = (const float*)d_in[1];
    const float* q_b    = (const float*)d_in[2];
    const float* kv_w   = (const float*)d_in[3];
    const float* kv_b   = (const float*)d_in[4];
    const float* proj_w = (const float*)d_in[5];
    const float* proj_b = (const float*)d_in[6];
    const float* rpb    = (const float*)d_in[7];
    float* out = (float*)d_out;

    char* ws = (char*)d_ws;
    ushort* xT    = (ushort*)(ws);                       //  6,291,456
    ushort* Qt    = (ushort*)(ws +  6291456);            //  6,291,456
    ushort* Kt    = (ushort*)(ws + 12582912);            //  6,291,456
    ushort* Vtc   = (ushort*)(ws + 18874368);            //  6,291,456
    ushort* O     = (ushort*)(ws + 25165824);            //  6,291,456
    float*  tabT  = (float*) (ws + 31457280);            //    190,512
    ushort* Wall  = (ushort*)(ws + 31647808);            //    884,736
    ushort* PW    = (ushort*)(ws + 32532544);            //    294,912
    float*  ballf = (float*) (ws + 32827456);            //      4,608

    setup      <<<dim3(1358), 256, 0, stream>>>(x, q_w, kv_w, proj_w, q_b, kv_b, rpb,
                                                xT, tabT, Wall, PW, ballf);
    qkv_gemm4  <<<dim3(8, 9, B_), 256, 0, stream>>>(xT, Wall, ballf, Qt, Kt, Vtc);
    attn4      <<<dim3(768), 256, 0, stream>>>(Qt, Kt, Vtc, tabT, O);
    proj_gemm3 <<<dim3(8, 3, B_), 256, 0, stream>>>(O, PW, proj_b, out);
}

// Round 7
// 150.868 us; speedup vs baseline: 1.7363x; 1.0110x over previous
//
#include <hip/hip_runtime.h>
#include <hip/hip_bf16.h>

#define B_  8
#define C_  384
#define N_  1024
#define NH_ 12
#define HD_ 32
#define D3_ 1152   // 3*C

typedef __bf16 bf16x8 __attribute__((ext_vector_type(8)));
typedef __bf16 bf16x2 __attribute__((ext_vector_type(2)));
typedef float  f32x4  __attribute__((ext_vector_type(4)));

typedef const __attribute__((address_space(1))) unsigned int guint;
typedef __attribute__((address_space(3))) unsigned int luint;

__device__ __forceinline__ float b2f(ushort u) {
    return __uint_as_float(((unsigned int)u) << 16);
}
__device__ __forceinline__ ushort f2b(float f) {
    unsigned int i = __float_as_uint(f);
    unsigned int r = i + 0x7fffu + ((i >> 16) & 1u);  // RNE
    return (ushort)(r >> 16);
}
// packed fp32x2 -> bf16x2 (RNE)
__device__ __forceinline__ unsigned pk2(float a, float b) {
#if __has_builtin(__builtin_amdgcn_cvt_pk_bf16_f32)
    bf16x2 t = __builtin_amdgcn_cvt_pk_bf16_f32(a, b);
    return __builtin_bit_cast(unsigned, t);
#else
    return (unsigned)f2b(a) | ((unsigned)f2b(b) << 16);
#endif
}

#if __has_builtin(__builtin_amdgcn_exp2f)
#define EXP2 __builtin_amdgcn_exp2f
#else
#define EXP2 exp2f
#endif

__device__ __forceinline__ void gl2lds16(const void* g, void* l) {
    __builtin_amdgcn_global_load_lds((guint*)g, (luint*)l, 16, 0, 0);
}

#define C1_ 0.25505654204433796f   // scale * log2e
#define C2_ 1.4426950408889634f    // log2e
#define TS_ 3972                   // padded per-head table stride (16B-aligned)

// ---------------------------------------------------------------------------
// setup: x-transpose + weight conversion + bias-table prep.
// Grid: [0,768) xtrans, [768,1346) prep, [1346,1358) tabT.
// tabT[h][i] = rpb[3968-i][h] * log2e   (full 2D reversal == 1D reversal)
// ---------------------------------------------------------------------------
__global__ __launch_bounds__(256) void setup(
    const float* __restrict__ x, const float* __restrict__ q_w,
    const float* __restrict__ kv_w, const float* __restrict__ proj_w,
    const float* __restrict__ q_b, const float* __restrict__ kv_b,
    const float* __restrict__ tab,
    ushort* __restrict__ xT, float* __restrict__ tabT,
    ushort* __restrict__ Wall, ushort* __restrict__ PW,
    float* __restrict__ ballf)
{
    __shared__ ushort T[64 * 72];
    const int bx = blockIdx.x, tid = threadIdx.x;

    if (bx < 768) {
        // ---- xtrans: x[b][c][n] fp32 -> xT[b][n][c] bf16 ----
        int t = bx;
        int nx = t & 15, cy = (t >> 4) % 6, b = t / 96;
        int n0 = nx * 64, c0 = cy * 64;
        {
            int i = tid >> 2;            // c-local
            int ns = (tid & 3) * 16;     // n-local
            const float* src = x + ((size_t)b * C_ + c0 + i) * N_ + n0 + ns;
            #pragma unroll
            for (int k4 = 0; k4 < 4; ++k4) {
                float4 f = *(const float4*)(src + k4 * 4);
                T[(ns + k4 * 4 + 0) * 72 + i] = f2b(f.x);
                T[(ns + k4 * 4 + 1) * 72 + i] = f2b(f.y);
                T[(ns + k4 * 4 + 2) * 72 + i] = f2b(f.z);
                T[(ns + k4 * 4 + 3) * 72 + i] = f2b(f.w);
            }
        }
        __syncthreads();
        {
            int j = tid >> 2;            // n-local
            int cs = (tid & 3) * 16;     // c-local
            ushort* dst = xT + ((size_t)b * N_ + n0 + j) * C_ + c0 + cs;
            *(uint4*)dst       = *(const uint4*)&T[j * 72 + cs];
            *(uint4*)(dst + 8) = *(const uint4*)&T[j * 72 + cs + 8];
        }
    } else if (bx < 1346) {
        // ---- prep: weights fp32 -> bf16; bias concat fp32 ----
        const int NW4 = 110592, NP4 = 36864, NB4 = 288;
        int t = (bx - 768) * 256 + tid;
        if (t < NW4) {
            int e = t * 4;
            float4 f = (e < 147456) ? *(const float4*)(q_w + e)
                                    : *(const float4*)(kv_w + e - 147456);
            union { uint2 u; ushort s[4]; } o;
            o.u.x = pk2(f.x, f.y); o.u.y = pk2(f.z, f.w);
            *(uint2*)(Wall + e) = o.u;
        } else if (t < NW4 + NP4) {
            int e = (t - NW4) * 4;
            float4 f = *(const float4*)(proj_w + e);
            union { uint2 u; ushort s[4]; } o;
            o.u.x = pk2(f.x, f.y); o.u.y = pk2(f.z, f.w);
            *(uint2*)(PW + e) = o.u;
        } else if (t < NW4 + NP4 + NB4) {
            int e = (t - NW4 - NP4) * 4;
            float4 f = (e < 384) ? *(const float4*)(q_b + e)
                                 : *(const float4*)(kv_b + e - 384);
            *(float4*)(ballf + e) = f;
        }
    } else {
        // ---- tabT: per-head fully-reversed, log2e-scaled table ----
        int h = bx - 1346;
        for (int i = tid; i < 3969; i += 256)
            tabT[h * TS_ + i] = tab[(size_t)(3968 - i) * NH_ + h] * C2_;
        // pad tail (read by vectorized prologue, never used in math)
        if (tid < 3) tabT[h * TS_ + 3969 + tid] = 0.0f;
    }
}

// ---------------------------------------------------------------------------
// qkv_gemm5: 128x128 tile, global_load_lds, XOR-swizzled LDS.
// Q/K blocks: W as A-operand (C rows = d) -> packed 8B stores to Qt/Kt[b][h][n][32].
// V blocks:   x as A-operand (C rows = n) -> fused-transpose packed stores to Vtc.
// Q pre-scaled by scale*log2e.
// ---------------------------------------------------------------------------
__global__ __launch_bounds__(256) void qkv_gemm5(
    const ushort* __restrict__ xT, const ushort* __restrict__ Wall,
    const float* __restrict__ ballf, ushort* __restrict__ Qt,
    ushort* __restrict__ Kt, ushort* __restrict__ Vtc)
{
    const int b = blockIdx.z, n0 = blockIdx.x * 128, d0 = blockIdx.y * 128;
    __shared__ ushort As[128 * 32];
    __shared__ ushort Bs[128 * 32];
    const int tid = threadIdx.x;
    const int lane = tid & 63, wave = tid >> 6;
    const int quad = lane >> 4, l16 = lane & 15;
    const int wn = (wave & 1) * 64, wd = (wave >> 1) * 64;

    f32x4 acc[4][4] = {};
    const ushort* xb = xT + ((size_t)b * N_ + n0) * C_;
    const ushort* wb = Wall + (size_t)d0 * C_;
    const int rowA = wave * 16 + (lane >> 2);
    const int fstage = ((lane >> 2) ^ (lane >> 4)) & 3;           // staging swizzle
    const int coff = ((lane & 3) ^ fstage) * 8;
    const int fread = ((l16 & 3) ^ ((l16 >> 2) & 3));             // read swizzle
    const bool isV = (d0 >= 768);

    for (int c0 = 0; c0 < C_; c0 += 32) {
        #pragma unroll
        for (int k = 0; k < 2; ++k) {
            gl2lds16(xb + (size_t)(k * 64 + rowA) * C_ + c0 + coff,
                     &As[(size_t)(k * 256 + wave * 64) * 8]);
            gl2lds16(wb + (size_t)(k * 64 + rowA) * C_ + c0 + coff,
                     &Bs[(size_t)(k * 256 + wave * 64) * 8]);
        }
        __syncthreads();
        bf16x8 af[4], bfr[4];
        #pragma unroll
        for (int i = 0; i < 4; ++i)
            af[i] = *(const bf16x8*)&As[(wn + i * 16 + l16) * 32 + (quad ^ fread) * 8];
        #pragma unroll
        for (int j = 0; j < 4; ++j)
            bfr[j] = *(const bf16x8*)&Bs[(wd + j * 16 + l16) * 32 + (quad ^ fread) * 8];
        if (!isV) {
            // C rows = d (W is A), cols = n
            #pragma unroll
            for (int i = 0; i < 4; ++i)
                #pragma unroll
                for (int j = 0; j < 4; ++j)
                    acc[i][j] = __builtin_amdgcn_mfma_f32_16x16x32_bf16(bfr[i], af[j], acc[i][j], 0, 0, 0);
        } else {
            // C rows = n (x is A), cols = d
            #pragma unroll
            for (int i = 0; i < 4; ++i)
                #pragma unroll
                for (int j = 0; j < 4; ++j)
                    acc[i][j] = __builtin_amdgcn_mfma_f32_16x16x32_bf16(af[i], bfr[j], acc[i][j], 0, 0, 0);
        }
        __syncthreads();
    }

    if (!isV) {
        // Q/K: lane holds 4 consecutive dc at fixed n -> packed uint2 stores
        ushort* dst = (d0 < 384) ? Qt : Kt;
        const float sc = (d0 < 384) ? C1_ : 1.0f;
        const int reg0 = (d0 < 384) ? 0 : 384;
        #pragma unroll
        for (int i = 0; i < 4; ++i) {
            int dloc = wd + i * 16;                // d-strip base (acc rows i)
            int dg = d0 - reg0 + dloc;
            int h = dg >> 5;
            int dc = (dg & 31) + quad * 4;
            float4 bvv = *(const float4*)(ballf + d0 + dloc + quad * 4);
            size_t hb = (size_t)(b * NH_ + h) * N_;
            #pragma unroll
            for (int j = 0; j < 4; ++j) {
                int n = n0 + wn + j * 16 + l16;
                uint2 w;
                w.x = pk2((acc[i][j][0] + bvv.x) * sc, (acc[i][j][1] + bvv.y) * sc);
                w.y = pk2((acc[i][j][2] + bvv.z) * sc, (acc[i][j][3] + bvv.w) * sc);
                *(uint2*)(dst + (hb + n) * 32 + dc) = w;
            }
        }
    } else {
        // V: fused transpose into Vtc[((bh*16+mc)*2+kc)*1024 + dc*32 + mm]
        #pragma unroll
        for (int j = 0; j < 4; ++j) {
            int dloc = wd + j * 16 + l16;
            int vd = d0 - 768 + dloc;
            int h = vd >> 5, dc = vd & 31;
            float bv = ballf[d0 + dloc];
            size_t hbase = (size_t)(b * NH_ + h) * 32768 + dc * 32;
            #pragma unroll
            for (int i = 0; i < 4; ++i) {
                int n = n0 + wn + i * 16 + quad * 4;
                size_t cbase = hbase + (size_t)((n >> 5)) * 1024 + (n & 31);
                uint2 w;
                w.x = pk2(acc[i][j][0] + bv, acc[i][j][1] + bv);
                w.y = pk2(acc[i][j][2] + bv, acc[i][j][3] + bv);
                *(uint2*)(Vtc + cbase) = w;
            }
        }
    }
}

// ---------------------------------------------------------------------------
// attn5: flash attention, S^T orientation; reversed bias table in LDS.
// Bias C-operands are natural-order float4 windows (conflict-free broadcasts):
//   I = ibx + mc*126 + (t>>1)*63 + (t&1)*16 + quad*4 + r,  ibx=(31-qy)*63+(31-qx)
// 6 shared 4-dword gathers/chunk cover both strips' 8 C-operands.
// ---------------------------------------------------------------------------
__global__ __launch_bounds__(256) void attn5(
    const ushort* __restrict__ Qt, const ushort* __restrict__ Kt,
    const ushort* __restrict__ Vtc, const float* __restrict__ tabT,
    ushort* __restrict__ O)
{
    const int bid = blockIdx.x;      // (b*12+h) + 96*nx
    const int bh96 = bid % 96;
    const int nx = bid / 96;
    const int b = bh96 / 12, h = bh96 % 12;

    __shared__ float tabL[TS_];
    __shared__ ushort Pa[8192];      // 4 waves x 2 strips x 16 x 64

    const int tid = threadIdx.x;
    const int lane = tid & 63, wave = tid >> 6;
    const int quad = lane >> 4, l16 = lane & 15;
    const int bh = b * NH_ + h;

    // vectorized table stage (float4; stride TS_ is 16B-aligned)
    {
        const float* th = tabT + h * TS_;
        int i = tid * 4;
        #pragma unroll
        for (int k = 0; k < 4; ++k) {
            if (i < TS_) *(float4*)&tabL[i] = *(const float4*)&th[i];
            i += 1024;
        }
    }
    __syncthreads();

    const int qs0 = nx * 8 + wave * 2;
    const ushort* Kbh = Kt + (size_t)bh * N_ * 32;
    const ushort* Vbh = Vtc + (size_t)bh * 16 * 2048;

    // Q B-frags (col=q=l16, k=dc=quad*8+j), one per strip
    bf16x8 qf[2];
    #pragma unroll
    for (int st = 0; st < 2; ++st) {
        int q = (qs0 + st) * 16 + l16;
        qf[st] = *(const bf16x8*)(Qt + ((size_t)bh * N_ + q) * 32 + quad * 8);
    }
    // reversed-table base for strip 0 (strip 1 = base - 16)
    int ibx0;
    {
        int q = qs0 * 16 + l16;
        ibx0 = (31 - (q >> 5)) * 63 + (31 - (q & 31));
    }

    f32x4 oacc[2][2] = {};
    float rs[2] = {0.f, 0.f};

    ushort* PwBase = &Pa[wave * 2048];
    const int pswz = l16 & 0xE;

    for (int mc = 0; mc < 16; ++mc) {
        // K A-frags: A[m=l16][k=quad*8+j] per 16-row tile (1KB line-contained)
        const ushort* kp = Kbh + mc * 64 * 32;
        bf16x8 k0 = *(const bf16x8*)(kp + (0 * 16 + l16) * 32 + quad * 8);
        bf16x8 k1 = *(const bf16x8*)(kp + (1 * 16 + l16) * 32 + quad * 8);
        bf16x8 k2 = *(const bf16x8*)(kp + (2 * 16 + l16) * 32 + quad * 8);
        bf16x8 k3 = *(const bf16x8*)(kp + (3 * 16 + l16) * 32 + quad * 8);
        // V^T A-frags: A[dc=dt*16+l16][m=kc*32+quad*8+j] (1KB line-contained)
        const ushort* vp = Vbh + mc * 2048;
        bf16x8 va[2][2];
        #pragma unroll
        for (int kc = 0; kc < 2; ++kc)
            #pragma unroll
            for (int dt = 0; dt < 2; ++dt)
                va[kc][dt] = *(const bf16x8*)(vp + kc * 1024 + (dt * 16 + l16) * 32 + quad * 8);

        // 6 shared bias gathers (natural-order float4 windows, broadcast-only)
        const float* Tb = tabL + ibx0 + mc * 126 + quad * 4;
        f32x4 tvm16, tv0, tv16, tv47, tv63, tv79;
        #pragma unroll
        for (int e = 0; e < 4; ++e) {
            tvm16[e] = Tb[e - 16];
            tv0[e]   = Tb[e];
            tv16[e]  = Tb[e + 16];
            tv47[e]  = Tb[e + 47];
            tv63[e]  = Tb[e + 63];
            tv79[e]  = Tb[e + 79];
        }
        // C-operand sets: st0 = {tv0, tv16, tv63, tv79}; st1 = {tvm16, tv0, tv47, tv63}
        f32x4 cbs[2][4] = {{tv0, tv16, tv63, tv79}, {tvm16, tv0, tv47, tv63}};

        #pragma unroll
        for (int st = 0; st < 2; ++st) {
            f32x4 s0 = __builtin_amdgcn_mfma_f32_16x16x32_bf16(k0, qf[st], cbs[st][0], 0, 0, 0);
            f32x4 s1 = __builtin_amdgcn_mfma_f32_16x16x32_bf16(k1, qf[st], cbs[st][1], 0, 0, 0);
            f32x4 s2 = __builtin_amdgcn_mfma_f32_16x16x32_bf16(k2, qf[st], cbs[st][2], 0, 0, 0);
            f32x4 s3 = __builtin_amdgcn_mfma_f32_16x16x32_bf16(k3, qf[st], cbs[st][3], 0, 0, 0);

            ushort* Pw = PwBase + st * 1024;
            f32x4 sv[4] = {s0, s1, s2, s3};
            #pragma unroll
            for (int t = 0; t < 4; ++t) {
                float p0 = EXP2(sv[t][0]);
                float p1 = EXP2(sv[t][1]);
                float p2 = EXP2(sv[t][2]);
                float p3 = EXP2(sv[t][3]);
                rs[st] += (p0 + p1) + (p2 + p3);
                uint2 w;
                w.x = pk2(p0, p1);
                w.y = pk2(p2, p3);
                *(uint2*)(Pw + l16 * 64 + (((t * 4 + quad) ^ pswz) * 4)) = w;
            }
            // PV: O^T[dc][q] += V^T . P   (B-frag P from swizzled LDS)
            #pragma unroll
            for (int kc = 0; kc < 2; ++kc) {
                bf16x8 pb = *(const bf16x8*)(Pw + l16 * 64 + (((kc * 8 + quad * 2) ^ pswz) * 4));
                oacc[st][0] = __builtin_amdgcn_mfma_f32_16x16x32_bf16(va[kc][0], pb, oacc[st][0], 0, 0, 0);
                oacc[st][1] = __builtin_amdgcn_mfma_f32_16x16x32_bf16(va[kc][1], pb, oacc[st][1], 0, 0, 0);
            }
        }
    }

    // row-sum: q fixed per lane; reduce across the 4 quads holding its m-slices
    #pragma unroll
    for (int st = 0; st < 2; ++st) {
        float s = rs[st];
        s += __shfl_xor(s, 16, 64);
        s += __shfl_xor(s, 32, 64);
        rs[st] = 1.0f / s;
    }

    // epilogue: O[b][q][h*32+dc], packed b64 stores
    #pragma unroll
    for (int st = 0; st < 2; ++st) {
        int q = (qs0 + st) * 16 + l16;
        ushort* ob = O + ((size_t)(b * N_ + q)) * C_ + h * HD_;
        #pragma unroll
        for (int dt = 0; dt < 2; ++dt) {
            uint2 w;
            w.x = pk2(oacc[st][dt][0] * rs[st], oacc[st][dt][1] * rs[st]);
            w.y = pk2(oacc[st][dt][2] * rs[st], oacc[st][dt][3] * rs[st]);
            *(uint2*)(ob + dt * 16 + quad * 4) = w;
        }
    }
}

// ---------------------------------------------------------------------------
// proj_gemm3: 128x128 tile, global_load_lds. A=PW[d][c], B=O[n][c].
// out[b][d][n] fp32 = acc + pb[d], coalesced along n.
// ---------------------------------------------------------------------------
__global__ __launch_bounds__(256) void proj_gemm3(
    const ushort* __restrict__ O, const ushort* __restrict__ PW,
    const float* __restrict__ pb, float* __restrict__ out)
{
    const int b = blockIdx.z, n0 = blockIdx.x * 128, d0 = blockIdx.y * 128;
    __shared__ ushort As[128 * 32];
    __shared__ ushort Bs[128 * 32];
    const int tid = threadIdx.x;
    const int lane = tid & 63, wave = tid >> 6;
    const int quad = lane >> 4, l16 = lane & 15;
    const int wa = (wave & 1) * 64, wb = (wave >> 1) * 64;

    f32x4 acc[4][4] = {};
    const ushort* ab = PW + (size_t)d0 * C_;
    const ushort* bbp = O + ((size_t)b * N_ + n0) * C_;
    const int rowA = wave * 16 + (lane >> 2);
    const int fstage = ((lane >> 2) ^ (lane >> 4)) & 3;
    const int coff = ((lane & 3) ^ fstage) * 8;
    const int fread = ((l16 & 3) ^ ((l16 >> 2) & 3));

    for (int c0 = 0; c0 < C_; c0 += 32) {
        #pragma unroll
        for (int k = 0; k < 2; ++k) {
            gl2lds16(ab + (size_t)(k * 64 + rowA) * C_ + c0 + coff,
                     &As[(size_t)(k * 256 + wave * 64) * 8]);
            gl2lds16(bbp + (size_t)(k * 64 + rowA) * C_ + c0 + coff,
                     &Bs[(size_t)(k * 256 + wave * 64) * 8]);
        }
        __syncthreads();
        bf16x8 af[4], bfr[4];
        #pragma unroll
        for (int i = 0; i < 4; ++i)
            af[i] = *(const bf16x8*)&As[(wa + i * 16 + l16) * 32 + (quad ^ fread) * 8];
        #pragma unroll
        for (int j = 0; j < 4; ++j)
            bfr[j] = *(const bf16x8*)&Bs[(wb + j * 16 + l16) * 32 + (quad ^ fread) * 8];
        #pragma unroll
        for (int i = 0; i < 4; ++i)
            #pragma unroll
            for (int j = 0; j < 4; ++j)
                acc[i][j] = __builtin_amdgcn_mfma_f32_16x16x32_bf16(af[i], bfr[j], acc[i][j], 0, 0, 0);
        __syncthreads();
    }

    #pragma unroll
    for (int i = 0; i < 4; ++i) {
        #pragma unroll
        for (int r = 0; r < 4; ++r) {
            int d = d0 + wa + i * 16 + quad * 4 + r;
            float bv = pb[d];
            float* op = out + ((size_t)b * C_ + d) * N_ + n0 + wb;
            #pragma unroll
            for (int j = 0; j < 4; ++j)
                op[j * 16 + l16] = acc[i][j][r] + bv;
        }
    }
}

// ---------------------------------------------------------------------------
extern "C" void kernel_launch(void* const* d_in, const int* in_sizes, int n_in,
                              void* d_out, int out_size, void* d_ws, size_t ws_size,
                              hipStream_t stream)
{
    const float* x      = (const float*)d_in[0];
    const float* q_w    = (const float*)d_in[1];
    const float* q_b    = (const float*)d_in[2];
    const float* kv_w   = (const float*)d_in[3];
    const float* kv_b   = (const float*)d_in[4];
    const float* proj_w = (const float*)d_in[5];
    const float* proj_b = (const float*)d_in[6];
    const float* rpb    = (const float*)d_in[7];
    float* out = (float*)d_out;

    char* ws = (char*)d_ws;
    ushort* xT    = (ushort*)(ws);                       //  6,291,456
    ushort* Qt    = (ushort*)(ws +  6291456);            //  6,291,456
    ushort* Kt    = (ushort*)(ws + 12582912);            //  6,291,456
    ushort* Vtc   = (ushort*)(ws + 18874368);            //  6,291,456
    ushort* O     = (ushort*)(ws + 25165824);            //  6,291,456
    float*  tabT  = (float*) (ws + 31457280);            //    190,656 (12 x 3972 x 4)
    ushort* Wall  = (ushort*)(ws + 31647936);            //    884,736
    ushort* PW    = (ushort*)(ws + 32532672);            //    294,912
    float*  ballf = (float*) (ws + 32827584);            //      4,608

    setup      <<<dim3(1358), 256, 0, stream>>>(x, q_w, kv_w, proj_w, q_b, kv_b, rpb,
                                                xT, tabT, Wall, PW, ballf);
    qkv_gemm5  <<<dim3(8, 9, B_), 256, 0, stream>>>(xT, Wall, ballf, Qt, Kt, Vtc);
    attn5      <<<dim3(768), 256, 0, stream>>>(Qt, Kt, Vtc, tabT, O);
    proj_gemm3 <<<dim3(8, 3, B_), 256, 0, stream>>>(O, PW, proj_b, out);
}